// Round 7
// baseline (299.873 us; speedup 1.0000x reference)
//
#include <hip/hip_runtime.h>

// FreqFusion forward, f32. Shapes fixed: B=2, C=256, CC=64, HR=128x128, LR=64x64.
// Scratch: d_ws unused. Intermediates live inside d_out (see layout in kernel_launch).
#define HWH 16384   // 128*128
#define HWL 4096    // 64*64
#define WH 128
#define WL 64

// ---------------- hamming helpers ----------------
__device__ __forceinline__ float ham3v(int t) {
    const float h[3] = {0.08f, 1.0f, 0.08f};
    return h[t / 3] * h[t % 3];
}
__device__ __forceinline__ float ham5v(int t) {
    const float h[5] = {0.08f, 0.54f, 1.0f, 0.54f, 0.08f};
    return h[t / 5] * h[t % 5];
}

// softmax over K*K ch, *ham, renorm  ==  exp(x-max)*ham / sum(exp(x-max)*ham)
template <int K>
__device__ __forceinline__ void normalize_post(float* m) {
    constexpr int K2 = K * K;
    float mx = -1e30f;
#pragma unroll
    for (int k = 0; k < K2; k++) mx = fmaxf(mx, m[k]);
    float s = 0.f;
#pragma unroll
    for (int k = 0; k < K2; k++) {
        float hv = (K == 3) ? ham3v(k) : ham5v(k);
        float e = __expf(m[k] - mx) * hv;
        m[k] = e;
        s += e;
    }
    float inv = 1.f / s;
#pragma unroll
    for (int k = 0; k < K2; k++) m[k] *= inv;
}

template <int K>
__device__ __forceinline__ void normalize_mask(const float* __restrict src, int stride,
                                               float* m) {
#pragma unroll
    for (int k = 0; k < K * K; k++) m[k] = src[(size_t)k * stride];
    normalize_post<K>(m);
}

template <int K>
__device__ __forceinline__ void normalize_mask2(const float* __restrict a,
                                                const float* __restrict b, int stride,
                                                float* m) {
#pragma unroll
    for (int k = 0; k < K * K; k++)
        m[k] = a[(size_t)k * stride] + b[(size_t)k * stride];
    normalize_post<K>(m);
}

// ---------------- weight prep: transpose to [ci][co] (co contiguous) ----------------
__global__ void prep_w_k(const float* __restrict Whr, const float* __restrict Wlr,
                         const float* __restrict Wenc, const float* __restrict Wenc2,
                         float* __restrict wbase) {
    int tid = blockIdx.x * blockDim.x + threadIdx.x;
    int stride = gridDim.x * blockDim.x;
    float* wt_hr = wbase;
    float* wt_lr = wbase + 16384;
    float* wtE = wbase + 32768;
    float* wtE2 = wbase + 51200;
    for (int i = tid; i < 16384; i += stride) {
        int ci = i >> 6, co = i & 63;
        wt_hr[i] = Whr[co * 256 + ci];
        wt_lr[i] = Wlr[co * 256 + ci];
    }
    for (int i = tid; i < 18432; i += stride) {
        int r = i >> 5, co = i & 31;
        int ci = r / 9, t = r % 9;
        wtE[i] = (co < 25) ? Wenc[(co * 64 + ci) * 9 + t] : 0.f;
    }
    for (int i = tid; i < 9216; i += stride) {
        int r = i >> 4, co = i & 15;
        int ci = r / 9, t = r % 9;
        wtE2[i] = (co < 9) ? Wenc2[(co * 64 + ci) * 9 + t] : 0.f;
    }
}

// ------------- 1x1 conv: 4 px/thread (float4), 8 co/thread ----------------
template <int HWp>
__device__ __forceinline__ void conv1x1_core4(const float* __restrict x,
                                              const float* __restrict wt,
                                              const float* __restrict bias,
                                              float* __restrict y, int n, int g, int px) {
    int co0 = g * 8;  // uniform
    const float* xb = x + (size_t)n * 256 * HWp + px;
    const float* w0 = wt + co0;
    float4 acc[8];
#pragma unroll
    for (int j = 0; j < 8; j++) acc[j] = make_float4(0.f, 0.f, 0.f, 0.f);
#pragma unroll 8
    for (int ci = 0; ci < 256; ci++) {
        float4 xv = *reinterpret_cast<const float4*>(xb + (size_t)ci * HWp);
        const float* wrow = w0 + ci * 64;  // uniform -> s_load
#pragma unroll
        for (int j = 0; j < 8; j++) {
            float wv = wrow[j];
            acc[j].x = fmaf(wv, xv.x, acc[j].x);
            acc[j].y = fmaf(wv, xv.y, acc[j].y);
            acc[j].z = fmaf(wv, xv.z, acc[j].z);
            acc[j].w = fmaf(wv, xv.w, acc[j].w);
        }
    }
#pragma unroll
    for (int j = 0; j < 8; j++) {
        float bv = bias[co0 + j];
        float4 r = make_float4(acc[j].x + bv, acc[j].y + bv, acc[j].z + bv, acc[j].w + bv);
        *reinterpret_cast<float4*>(y + ((size_t)(n * 64 + co0 + j)) * HWp + px) = r;
    }
}

__global__ __launch_bounds__(256) void conv1x1_all_k(
    const float* __restrict hr, const float* __restrict lrf, const float* __restrict wt_hr,
    const float* __restrict wt_lr, const float* __restrict bhr, const float* __restrict blr,
    float* __restrict chf, float* __restrict clf, int N) {
    const int HRB = 16 * N * 8;  // 256 for N=2
    int b = blockIdx.x;
    if (b < HRB) {
        int pxb = b % 16;
        int n = (b / 16) % N;
        int g = b / (16 * N);
        int px = 4 * (pxb * 256 + (int)threadIdx.x);
        conv1x1_core4<HWH>(hr, wt_hr, bhr, chf, n, g, px);
    } else {
        int b2 = b - HRB;
        int pxb = b2 % 4;
        int n = (b2 / 4) % N;
        int g = b2 / (4 * N);
        int px = 4 * (pxb * 256 + (int)threadIdx.x);
        conv1x1_core4<HWL>(lrf, wt_lr, blr, clf, n, g, px);
    }
}

// ------------- 3x3 conv, LDS-tiled: all-CH co per block, ci staged in 16-chunks -----------
// block tile: ROWS x WW output px (256 threads), smem tile: 16ci x (ROWS+2) x (WW+2)
template <int COUT, int CH, int PAD, int LOG2W, int HH, int WW, int ROWS, int CIPB>
__device__ __forceinline__ void conv3x3_tile(const float* __restrict x,
                                             const float* __restrict wt,
                                             const float* __restrict bias,
                                             float* __restrict y, float* __restrict sm,
                                             int n, int g, int yt, int ci0, bool addb) {
    constexpr int TW = WW + 2;
    constexpr int CICH = 16;
    constexpr int STAGE = CICH * (ROWS + 2) * TW;
    int y0 = yt * ROWS;
    int ly = threadIdx.x >> LOG2W;
    int lx = threadIdx.x & (WW - 1);
    int px = (y0 + ly) * WW + lx;
    int co0 = g * CH;  // uniform
    float acc[CH];
#pragma unroll
    for (int j = 0; j < CH; j++) {
        int co = co0 + j;
        acc[j] = (addb && co < COUT) ? bias[co] : 0.f;
    }
    for (int cc = 0; cc < CIPB; cc += CICH) {
        const float* xb = x + ((size_t)(n * 64 + ci0 + cc)) * (HH * WW);
        for (int e = threadIdx.x; e < STAGE; e += 256) {
            int c = e / ((ROWS + 2) * TW);
            int rem = e % ((ROWS + 2) * TW);
            int r = rem / TW, col = rem % TW;
            int gy = y0 + r - 1, gx = col - 1;
            float v = 0.f;
            if (gy >= 0 && gy < HH && gx >= 0 && gx < WW)
                v = xb[(size_t)c * (HH * WW) + gy * WW + gx];
            sm[e] = v;
        }
        __syncthreads();
        for (int ci = 0; ci < CICH; ci++) {
            const float* tp = sm + (ci * (ROWS + 2) + ly) * TW + lx;
            float a0 = tp[0], a1 = tp[1], a2 = tp[2];
            float b0 = tp[TW], b1 = tp[TW + 1], b2 = tp[TW + 2];
            float c0 = tp[2 * TW], c1 = tp[2 * TW + 1], c2 = tp[2 * TW + 2];
            const float* wb = wt + (size_t)((ci0 + cc + ci) * 9) * PAD + co0;  // uniform
#pragma unroll
            for (int j = 0; j < CH; j++) {
                float s = acc[j];
                s = fmaf(wb[0 * PAD + j], a0, s);
                s = fmaf(wb[1 * PAD + j], a1, s);
                s = fmaf(wb[2 * PAD + j], a2, s);
                s = fmaf(wb[3 * PAD + j], b0, s);
                s = fmaf(wb[4 * PAD + j], b1, s);
                s = fmaf(wb[5 * PAD + j], b2, s);
                s = fmaf(wb[6 * PAD + j], c0, s);
                s = fmaf(wb[7 * PAD + j], c1, s);
                s = fmaf(wb[8 * PAD + j], c2, s);
                acc[j] = s;
            }
        }
        __syncthreads();
    }
#pragma unroll
    for (int j = 0; j < CH; j++) {
        int co = co0 + j;
        if (co < COUT) y[((size_t)(n * COUT + co)) * (HH * WW) + px] = acc[j];
    }
}

// merged: G (clf->g_out, 25co), K (clf->k_out, 9co), C (chf->m_hrhr partials, ci-split)
// heavy G/K blocks at LOW blockIdx so they dispatch first.
__global__ __launch_bounds__(256) void conv3x3_CGK_k(
    const float* __restrict chf, const float* __restrict clf, const float* __restrict wtE,
    const float* __restrict wtE2, const float* __restrict benc,
    const float* __restrict benc2, float* __restrict m_hrhr_pA, float* __restrict m_hrhr_pB,
    float* __restrict g_out, float* __restrict k_out, int N) {
    __shared__ float smem[16 * 4 * 130];  // 33280 B (C shape is the max)
    const int GBl = 16 * N * 2, KBl = 16 * N;
    int b = blockIdx.x;
    if (b < GBl) {
        int yt = b % 16;
        int n = (b / 16) % N;
        int g = b / (16 * N);
        conv3x3_tile<25, 13, 32, 6, WL, WL, 4, 64>(clf, wtE, benc, g_out, smem, n, g, yt, 0,
                                                   true);
    } else if (b < GBl + KBl) {
        int t = b - GBl;
        int yt = t % 16;
        int n = t / 16;
        conv3x3_tile<9, 9, 16, 6, WL, WL, 4, 64>(clf, wtE2, benc2, k_out, smem, n, 0, yt, 0,
                                                 true);
    } else {
        int t = b - GBl - KBl;
        int yt = t % 64;
        t /= 64;
        int n = t % N;
        int s = t / N;
        conv3x3_tile<9, 9, 16, 7, WH, WH, 2, 32>(chf, wtE2, benc2, s ? m_hrhr_pB : m_hrhr_pA,
                                                 smem, n, 0, yt, s * 32, s == 0);
    }
}

// F: chf2 -> m_lrhr partials (25co, co-split 2, ci-split 2)
__global__ __launch_bounds__(256) void conv3x3_F_k(const float* __restrict chf2,
                                                   const float* __restrict wtE,
                                                   const float* __restrict benc,
                                                   float* __restrict pA,
                                                   float* __restrict pB, int N) {
    __shared__ float smem[16 * 4 * 130];
    int t = blockIdx.x;
    int yt = t % 64;
    t /= 64;
    int n = t % N;
    t /= N;
    int g = t % 2;
    int s = t / 2;
    conv3x3_tile<25, 13, 32, 7, WH, WH, 2, 32>(chf2, wtE, benc, s ? pB : pA, smem, n, g, yt,
                                               s * 32, s == 0);
}

// ------- stage D+E: chf2 = 2*chf - carafe(chf, norm(m_hrhr), k=3, up=1), 8 ch-groups -------
__global__ void fuse_de_k(const float* __restrict chf, const float* __restrict mA,
                          const float* __restrict mB, float* __restrict chf2, int N) {
    int b = blockIdx.x;
    int pxb = b % 64;
    int n = (b / 64) % N;
    int c0 = (b / (64 * N)) * 8;
    int px = pxb * 256 + threadIdx.x;
    int yy = px >> 7, xx = px & 127;
    float m[9];
    normalize_mask2<3>(mA + (size_t)n * 9 * HWH + px, mB + (size_t)n * 9 * HWH + px, HWH, m);
    int offs[9];
    float mm[9];
#pragma unroll
    for (int t = 0; t < 9; t++) {
        int sy = yy + t / 3 - 1, sx = xx + t % 3 - 1;
        bool ok = (sy >= 0 && sy < WH && sx >= 0 && sx < WH);
        offs[t] = ok ? sy * WH + sx : 0;
        mm[t] = ok ? m[t] : 0.f;
    }
    const float* cb = chf + (size_t)n * 64 * HWH;
    float* ob = chf2 + (size_t)n * 64 * HWH + px;
#pragma unroll
    for (int c = c0; c < c0 + 8; c++) {
        const float* xc = cb + (size_t)c * HWH;
        float s = 0.f, center = 0.f;
#pragma unroll
        for (int t = 0; t < 9; t++) {
            float xv = xc[offs[t]];
            if (t == 4) center = xv;
            s = fmaf(mm[t], xv, s);
        }
        ob[(size_t)c * HWH] = 2.f * center - s;
    }
}

// ---- stage H+I: mask_lr = (m_lrhr) + carafe(g_out, norm(m_lrhr), k=5, up=2) ----
__global__ void fuse_hi_k(const float* __restrict mA, const float* __restrict mB,
                          const float* __restrict g, float* __restrict mask_lr, int N) {
    int b = blockIdx.x;
    int pxb = b % 64;
    int n = (b / 64) % N;
    int co0 = (b / (64 * N)) * 5;
    int px = pxb * 256 + threadIdx.x;
    int Y = px >> 7, X = px & 127;
    int h = Y >> 1, w = X >> 1;
    const float* mbA = mA + (size_t)n * 25 * HWH + px;
    const float* mbB = mB + (size_t)n * 25 * HWH + px;
    float m[25];
    normalize_mask2<5>(mbA, mbB, HWH, m);
    float acc[5];
#pragma unroll
    for (int j = 0; j < 5; j++) acc[j] = 0.f;
    const float* gb = g + ((size_t)n * 25 + co0) * HWL;
    for (int k = 0; k < 25; k++) {
        int sy = h + k / 5 - 2, sx = w + k % 5 - 2;
        if (sy >= 0 && sy < WL && sx >= 0 && sx < WL) {
            int off = sy * WL + sx;
            float mk = m[k];
#pragma unroll
            for (int j = 0; j < 5; j++)
                acc[j] = fmaf(mk, gb[(size_t)j * HWL + off], acc[j]);
        }
    }
#pragma unroll
    for (int j = 0; j < 5; j++)
        mask_lr[((size_t)(n * 25 + co0 + j)) * HWH + px] =
            mbA[(size_t)(co0 + j) * HWH] + mbB[(size_t)(co0 + j) * HWH] + acc[j];
}

// ---------------- normalize mask_lr -> out0; 64-thr blocks ----------------
__global__ void norm25_k(const float* __restrict mask_lr, float* __restrict out0, int N) {
    int b = blockIdx.x;
    int pxb = b % 256;
    int n = b / 256;
    int px = pxb * 64 + threadIdx.x;
    float m[25];
    normalize_mask<5>(mask_lr + (size_t)n * 25 * HWH + px, HWH, m);
#pragma unroll
    for (int k = 0; k < 25; k++) out0[((size_t)(n * 25 + k)) * HWH + px] = m[k];
}

// ---- stage L: mask_hr = (m_hrhr) + carafe(k_out, out0, k=5, up=2); 3 co-groups of 3 ----
__global__ void fuse_l_k(const float* __restrict m_n, const float* __restrict kf,
                         const float* __restrict mhA, const float* __restrict mhB,
                         float* __restrict mask_hr, int N) {
    int b = blockIdx.x;
    int pxb = b % 64;
    int n = (b / 64) % N;
    int co0 = (b / (64 * N)) * 3;
    int px = pxb * 256 + threadIdx.x;
    int Y = px >> 7, X = px & 127;
    int h = Y >> 1, w = X >> 1;
    float m[25];
#pragma unroll
    for (int k = 0; k < 25; k++) m[k] = m_n[((size_t)(n * 25 + k)) * HWH + px];
    float acc[3];
#pragma unroll
    for (int j = 0; j < 3; j++) acc[j] = 0.f;
    const float* kb = kf + ((size_t)n * 9 + co0) * HWL;
    for (int k = 0; k < 25; k++) {
        int sy = h + k / 5 - 2, sx = w + k % 5 - 2;
        if (sy >= 0 && sy < WL && sx >= 0 && sx < WL) {
            int off = sy * WL + sx;
            float mk = m[k];
#pragma unroll
            for (int j = 0; j < 3; j++)
                acc[j] = fmaf(mk, kb[(size_t)j * HWL + off], acc[j]);
        }
    }
#pragma unroll
    for (int j = 0; j < 3; j++)
        mask_hr[((size_t)(n * 9 + co0 + j)) * HWH + px] =
            mhA[((size_t)(n * 9 + co0 + j)) * HWH + px] +
            mhB[((size_t)(n * 9 + co0 + j)) * HWH + px] + acc[j];
}

// ------------- hr_out = 2*hr - carafe(hr, norm(mask_hr), k=3, up=1) -> O1 -------------
#define HRCHG 8
__global__ __launch_bounds__(256) void hr_out_k(const float* __restrict mask_hr,
                                                const float* __restrict hr,
                                                float* __restrict out1, int N) {
    __shared__ float tile[HRCHG][10][132];  // 42240 B
    int b = blockIdx.x;
    int yt = b & 15;
    int g = (b >> 4) & 31;
    int n = b >> 9;
    int y0 = yt * 8;
    int c0 = g * HRCHG;
    const float* hb = hr + ((size_t)n * 256 + c0) * HWH;
    for (int e = threadIdx.x; e < HRCHG * 10 * 132; e += 256) {
        int c = e / (10 * 132);
        int rem = e % (10 * 132);
        int r = rem / 132, col = rem % 132;
        int y = y0 + r - 1, x = col - 1;
        float v = 0.f;
        if (y >= 0 && y < WH && x >= 0 && x < WH) v = hb[(size_t)c * HWH + y * WH + x];
        tile[c][r][col] = v;
    }
    __syncthreads();
    float* ob = out1 + ((size_t)n * 256 + c0) * HWH;
#pragma unroll
    for (int i = 0; i < 4; i++) {
        int lp = threadIdx.x + 256 * i;
        int ly = lp >> 7, lx = lp & 127;
        int px = (y0 + ly) * WH + lx;
        float m[9];
        normalize_mask<3>(mask_hr + (size_t)n * 9 * HWH + px, HWH, m);
        for (int c = 0; c < HRCHG; c++) {
            float center = tile[c][ly + 1][lx + 1];
            float s = 0.f;
#pragma unroll
            for (int t = 0; t < 9; t++)
                s = fmaf(m[t], tile[c][ly + t / 3][lx + t % 3], s);
            ob[(size_t)c * HWH + px] = 2.f * center - s;
        }
    }
}

// ------- lr_out = carafe(lr_feat, out0, k=5, up=2) -> O2 (runs LAST) -------
#define LRCHG 16
__global__ __launch_bounds__(256, 1) void lr_out_k(const float* __restrict m_n,
                                                   const float* __restrict lr,
                                                   float* __restrict out2, int N) {
    __shared__ float tile[LRCHG][12][68];  // 52224 B
    int b = blockIdx.x;
    int yt = b & 7;
    int g = (b >> 3) & 15;
    int n = b >> 7;
    int y0 = yt * 16;
    int hbase = y0 >> 1;
    int c0 = g * LRCHG;
    const float* lrb = lr + ((size_t)n * 256 + c0) * HWL;
    for (int e = threadIdx.x; e < LRCHG * 12 * 68; e += 256) {
        int c = e / (12 * 68);
        int rem = e % (12 * 68);
        int r = rem / 68, col = rem % 68;
        int h = hbase + r - 2, w = col - 2;
        float v = 0.f;
        if (h >= 0 && h < WL && w >= 0 && w < WL) v = lrb[(size_t)c * HWL + h * WL + w];
        tile[c][r][col] = v;
    }
    __syncthreads();
    const float* mb = m_n + (size_t)n * 25 * HWH;
    float* ob = out2 + ((size_t)n * 256 + c0) * HWH;
#pragma unroll
    for (int i = 0; i < 2; i++) {
        int q = threadIdx.x + 256 * i;
        int qy = q >> 6, qx = q & 63;
        int Y0 = y0 + 2 * qy;
        int X0 = 2 * qx;
        float2 mk0[25], mk1[25];
#pragma unroll
        for (int k = 0; k < 25; k++) {
            mk0[k] = *(const float2*)(mb + (size_t)k * HWH + Y0 * WH + X0);
            mk1[k] = *(const float2*)(mb + (size_t)k * HWH + (Y0 + 1) * WH + X0);
        }
        for (int c = 0; c < LRCHG; c++) {
            float a00 = 0.f, a01 = 0.f, a10 = 0.f, a11 = 0.f;
#pragma unroll
            for (int k = 0; k < 25; k++) {
                float v = tile[c][qy + k / 5][qx + k % 5];
                a00 = fmaf(mk0[k].x, v, a00);
                a01 = fmaf(mk0[k].y, v, a01);
                a10 = fmaf(mk1[k].x, v, a10);
                a11 = fmaf(mk1[k].y, v, a11);
            }
            float* op = ob + (size_t)c * HWH + (size_t)Y0 * WH + X0;
            *(float2*)op = make_float2(a00, a01);
            *(float2*)(op + WH) = make_float2(a10, a11);
        }
    }
}

extern "C" void kernel_launch(void* const* d_in, const int* in_sizes, int n_in, void* d_out,
                              int out_size, void* d_ws, size_t ws_size, hipStream_t stream) {
    const float* hr = (const float*)d_in[0];
    const float* lr = (const float*)d_in[1];
    const float* Whr = (const float*)d_in[2];
    const float* bhr = (const float*)d_in[3];
    const float* Wlr = (const float*)d_in[4];
    const float* blr = (const float*)d_in[5];
    const float* Wenc = (const float*)d_in[6];
    const float* benc = (const float*)d_in[7];
    const float* Wenc2 = (const float*)d_in[8];
    const float* benc2 = (const float*)d_in[9];
    float* out = (float*)d_out;
    const int B = in_sizes[0] / (256 * HWH);  // 2
    (void)d_ws; (void)ws_size;

    float* out0 = out;                           // B*25*HWH  (final: mask_lr_n)
    float* O1 = out + (size_t)B * 25 * HWH;      // B*256*HWH (final: hr_out)
    float* O2 = O1 + (size_t)B * 256 * HWH;      // B*256*HWH (final: lr_out)

    // --- scratch inside O2 (dead before lr_out_k overwrites O2) ---
    float* wbase = O2;                                // 60416 floats of weights
    float* wt_hr = wbase;
    float* wt_lr = wbase + 16384;
    float* wtE = wbase + 32768;
    float* wtE2 = wbase + 51200;
    float* mask_hr = O2 + 60416;                      // B*9*HWH

    // --- scratch inside O1 (dead before hr_out_k overwrites O1); total 8,044,544 < 8,388,608
    float* chf = O1;                                  // B*64*HWH
    float* chf2 = chf + (size_t)B * 64 * HWH;
    float* clf = chf2 + (size_t)B * 64 * HWH;         // B*64*HWL
    float* m_hrhr_pA = clf + (size_t)B * 64 * HWL;    // B*9*HWH
    float* m_hrhr_pB = m_hrhr_pA + (size_t)B * 9 * HWH;
    float* m_lrhr_pA = m_hrhr_pB + (size_t)B * 9 * HWH;   // B*25*HWH
    float* m_lrhr_pB = m_lrhr_pA + (size_t)B * 25 * HWH;
    float* g_out = m_lrhr_pB + (size_t)B * 25 * HWH;  // B*25*HWL
    float* k_out = g_out + (size_t)B * 25 * HWL;      // B*9*HWL
    float* mask_lr = k_out + (size_t)B * 9 * HWL;     // B*25*HWH

    prep_w_k<<<64, 256, 0, stream>>>(Whr, Wlr, Wenc, Wenc2, wbase);
    // A+B: 1x1 convs, float4-vectorized (hr: 16*B*8, lr: 4*B*8 blocks)
    conv1x1_all_k<<<16 * B * 8 + 4 * B * 8, 256, 0, stream>>>(hr, lr, wt_hr, wt_lr, bhr,
                                                              blr, chf, clf, B);
    // G + K + C merged, LDS-tiled (G: 16*B*2, K: 16*B, C: 64*B*2)
    conv3x3_CGK_k<<<16 * B * 2 + 16 * B + 64 * B * 2, 256, 0, stream>>>(
        chf, clf, wtE, wtE2, benc, benc2, m_hrhr_pA, m_hrhr_pB, g_out, k_out, B);
    // D+E: chf2
    fuse_de_k<<<64 * B * 8, 256, 0, stream>>>(chf, m_hrhr_pA, m_hrhr_pB, chf2, B);
    // F: chf2 -> m_lrhr partials, LDS-tiled (64*B*2co*2ci blocks)
    conv3x3_F_k<<<64 * B * 4, 256, 0, stream>>>(chf2, wtE, benc, m_lrhr_pA, m_lrhr_pB, B);
    // H+I: mask_lr
    fuse_hi_k<<<64 * B * 5, 256, 0, stream>>>(m_lrhr_pA, m_lrhr_pB, g_out, mask_lr, B);
    // J: out0 = normalize(mask_lr)
    norm25_k<<<256 * B, 64, 0, stream>>>(mask_lr, out0, B);
    // L: mask_hr
    fuse_l_k<<<64 * B * 3, 256, 0, stream>>>(out0, k_out, m_hrhr_pA, m_hrhr_pB, mask_hr, B);
    // M+O: hr_out -> O1 (LDS-tiled)
    hr_out_k<<<B * 512, 256, 0, stream>>>(mask_hr, hr, O1, B);
    // N: lr_out -> O2 (LDS-tiled)
    lr_out_k<<<B * 128, 256, 0, stream>>>(out0, lr, O2, B);
}

// Round 8
// 289.626 us; speedup vs baseline: 1.0354x; 1.0354x over previous
//
#include <hip/hip_runtime.h>

// FreqFusion forward, f32. Shapes fixed: B=2, C=256, CC=64, HR=128x128, LR=64x64.
// Scratch: d_ws unused. Intermediates live inside d_out (see layout in kernel_launch).
#define HWH 16384   // 128*128
#define HWL 4096    // 64*64
#define WH 128
#define WL 64

// ---------------- hamming helpers ----------------
__device__ __forceinline__ float ham3v(int t) {
    const float h[3] = {0.08f, 1.0f, 0.08f};
    return h[t / 3] * h[t % 3];
}
__device__ __forceinline__ float ham5v(int t) {
    const float h[5] = {0.08f, 0.54f, 1.0f, 0.54f, 0.08f};
    return h[t / 5] * h[t % 5];
}

// softmax over K*K ch, *ham, renorm  ==  exp(x-max)*ham / sum(exp(x-max)*ham)
template <int K>
__device__ __forceinline__ void normalize_post(float* m) {
    constexpr int K2 = K * K;
    float mx = -1e30f;
#pragma unroll
    for (int k = 0; k < K2; k++) mx = fmaxf(mx, m[k]);
    float s = 0.f;
#pragma unroll
    for (int k = 0; k < K2; k++) {
        float hv = (K == 3) ? ham3v(k) : ham5v(k);
        float e = __expf(m[k] - mx) * hv;
        m[k] = e;
        s += e;
    }
    float inv = 1.f / s;
#pragma unroll
    for (int k = 0; k < K2; k++) m[k] *= inv;
}

template <int K>
__device__ __forceinline__ void normalize_mask(const float* __restrict src, int stride,
                                               float* m) {
#pragma unroll
    for (int k = 0; k < K * K; k++) m[k] = src[(size_t)k * stride];
    normalize_post<K>(m);
}

template <int K>
__device__ __forceinline__ void normalize_mask2(const float* __restrict a,
                                                const float* __restrict b, int stride,
                                                float* m) {
#pragma unroll
    for (int k = 0; k < K * K; k++)
        m[k] = a[(size_t)k * stride] + b[(size_t)k * stride];
    normalize_post<K>(m);
}

// unaligned float4 load (gfx950 supports unaligned VMEM; compiler may split)
struct F4 { float x, y, z, w; };
__device__ __forceinline__ F4 ld4u(const float* p) {
    F4 v;
    __builtin_memcpy(&v, p, 16);
    return v;
}

// ---------------- weight prep: transpose to [ci][co] (co contiguous) ----------------
__global__ void prep_w_k(const float* __restrict Whr, const float* __restrict Wlr,
                         const float* __restrict Wenc, const float* __restrict Wenc2,
                         float* __restrict wbase) {
    int tid = blockIdx.x * blockDim.x + threadIdx.x;
    int stride = gridDim.x * blockDim.x;
    float* wt_hr = wbase;
    float* wt_lr = wbase + 16384;
    float* wtE = wbase + 32768;
    float* wtE2 = wbase + 51200;
    for (int i = tid; i < 16384; i += stride) {
        int ci = i >> 6, co = i & 63;
        wt_hr[i] = Whr[co * 256 + ci];
        wt_lr[i] = Wlr[co * 256 + ci];
    }
    for (int i = tid; i < 18432; i += stride) {
        int r = i >> 5, co = i & 31;
        int ci = r / 9, t = r % 9;
        wtE[i] = (co < 25) ? Wenc[(co * 64 + ci) * 9 + t] : 0.f;
    }
    for (int i = tid; i < 9216; i += stride) {
        int r = i >> 4, co = i & 15;
        int ci = r / 9, t = r % 9;
        wtE2[i] = (co < 9) ? Wenc2[(co * 64 + ci) * 9 + t] : 0.f;
    }
}

// ------------- 1x1 conv as LDS-GEMM: stage 256ci x 64px (64KB), one barrier -------------
// thread: (px-lane, co-quarter of 16); per ci: 1 ds_read + 16 FMA. Input read ONCE.
__global__ __launch_bounds__(256) void conv1x1_all_k(
    const float* __restrict hr, const float* __restrict lrf, const float* __restrict wt_hr,
    const float* __restrict wt_lr, const float* __restrict bhr, const float* __restrict blr,
    float* __restrict chf, float* __restrict clf, int N) {
    __shared__ float sm[16384];  // 64 KB
    int b = blockIdx.x;
    const int HRB = (HWH / 64) * N;  // 512
    const float *x, *wt, *bias;
    float* y;
    int HWp, n, px0;
    if (b < HRB) {
        x = hr; wt = wt_hr; bias = bhr; y = chf; HWp = HWH;
        n = b / (HWH / 64);
        px0 = (b % (HWH / 64)) * 64;
    } else {
        int b2 = b - HRB;
        x = lrf; wt = wt_lr; bias = blr; y = clf; HWp = HWL;
        n = b2 / (HWL / 64);
        px0 = (b2 % (HWL / 64)) * 64;
    }
    const float* xb = x + (size_t)n * 256 * HWp + px0;
    for (int e = threadIdx.x; e < 4096; e += 256) {
        int ci = e >> 4, q = e & 15;
        *reinterpret_cast<float4*>(sm + ci * 64 + q * 4) =
            *reinterpret_cast<const float4*>(xb + (size_t)ci * HWp + q * 4);
    }
    __syncthreads();
    int pl = threadIdx.x & 63;
    int cq = threadIdx.x >> 6;  // wave-uniform
    int co0 = cq * 16;
    float acc[16];
#pragma unroll
    for (int j = 0; j < 16; j++) acc[j] = 0.f;
    const float* w0 = wt + co0;
#pragma unroll 8
    for (int ci = 0; ci < 256; ci++) {
        float xv = sm[ci * 64 + pl];
        const float* wr = w0 + ci * 64;  // uniform -> s_load
#pragma unroll
        for (int j = 0; j < 16; j++) acc[j] = fmaf(wr[j], xv, acc[j]);
    }
    float* yb = y + ((size_t)(n * 64 + co0)) * HWp + px0 + pl;
#pragma unroll
    for (int j = 0; j < 16; j++) yb[(size_t)j * HWp] = acc[j] + bias[co0 + j];
}

// ------------- 3x3 conv, 2px/thread: 3 float4 row-loads -> 18*CH FMA per ci -------------
template <int COUT, int CH, int PAD, int LOG2W, int HH, int WW, int NCI>
__device__ __forceinline__ void conv3x3_2px(const float* __restrict x,
                                            const float* __restrict wt,
                                            const float* __restrict bias,
                                            float* __restrict y, int n, int g, int pxh,
                                            int ci0, bool addb) {
    constexpr int HWp = HH * WW;
    int px = pxh * 2;
    int yy = px >> LOG2W, xx = px & (WW - 1);
    int co0 = g * CH;  // uniform
    float a0[CH], a1[CH];
#pragma unroll
    for (int j = 0; j < CH; j++) { a0[j] = 0.f; a1[j] = 0.f; }
    const float* xb = x + (size_t)(n * 64 + ci0) * HWp;
    const float* wb0 = wt + (size_t)ci0 * 9 * PAD + co0;
    int roff[3];
    bool rv[3];
#pragma unroll
    for (int r = 0; r < 3; r++) {
        int sy = yy + r - 1;
        rv[r] = (sy >= 0) && (sy < HH);
        roff[r] = sy * WW + xx - 1;
    }
    bool lv = (xx > 0), rgv = (xx < WW - 2);
    for (int ci = 0; ci < NCI; ci++) {
        const float* xc = xb + (size_t)ci * HWp;
        const float* w = wb0 + (size_t)ci * 9 * PAD;
#pragma unroll
        for (int r = 0; r < 3; r++) {
            F4 v = ld4u(xc + roff[r]);  // neighbor-plane reads stay inside d_out; masked below
            float t0 = (rv[r] && lv) ? v.x : 0.f;
            float t1 = rv[r] ? v.y : 0.f;
            float t2 = rv[r] ? v.z : 0.f;
            float t3 = (rv[r] && rgv) ? v.w : 0.f;
#pragma unroll
            for (int j = 0; j < CH; j++) {
                float w0 = w[(r * 3 + 0) * PAD + j];
                float w1 = w[(r * 3 + 1) * PAD + j];
                float w2 = w[(r * 3 + 2) * PAD + j];
                a0[j] = fmaf(w0, t0, fmaf(w1, t1, fmaf(w2, t2, a0[j])));
                a1[j] = fmaf(w0, t1, fmaf(w1, t2, fmaf(w2, t3, a1[j])));
            }
        }
    }
#pragma unroll
    for (int j = 0; j < CH; j++) {
        int co = co0 + j;
        if (co < COUT) {
            float bv = addb ? bias[co] : 0.f;
            float* op = y + ((size_t)(n * COUT + co)) * HWp + px;
            *reinterpret_cast<float2*>(op) = make_float2(a0[j] + bv, a1[j] + bv);
        }
    }
}

// merged: G (clf->g_out, co5x5), K (clf->k_out, co2x5), C (chf->m_hrhr partials, co3x3, ci2)
__global__ __launch_bounds__(256) void conv3x3_CGK_k(
    const float* __restrict chf, const float* __restrict clf, const float* __restrict wtE,
    const float* __restrict wtE2, const float* __restrict benc,
    const float* __restrict benc2, float* __restrict m_hrhr_pA, float* __restrict m_hrhr_pB,
    float* __restrict g_out, float* __restrict k_out, int N) {
    const int GB = 8 * N * 5, KB = 8 * N * 2;
    int b = blockIdx.x;
    if (b < GB) {
        int pxb = b % 8;
        int n = (b / 8) % N;
        int g = b / (8 * N);
        conv3x3_2px<25, 5, 32, 6, WL, WL, 64>(clf, wtE, benc, g_out, n, g,
                                              pxb * 256 + (int)threadIdx.x, 0, true);
    } else if (b < GB + KB) {
        int t = b - GB;
        int pxb = t % 8;
        int n = (t / 8) % N;
        int g = t / (8 * N);
        conv3x3_2px<9, 5, 16, 6, WL, WL, 64>(clf, wtE2, benc2, k_out, n, g,
                                             pxb * 256 + (int)threadIdx.x, 0, true);
    } else {
        int t = b - GB - KB;
        int pxb = t % 32; t /= 32;
        int n = t % N; t /= N;
        int g = t % 3;
        int s = t / 3;
        conv3x3_2px<9, 3, 16, 7, WH, WH, 32>(chf, wtE2, benc2, s ? m_hrhr_pB : m_hrhr_pA,
                                             n, g, pxb * 256 + (int)threadIdx.x, s * 32,
                                             s == 0);
    }
}

// F: chf2 -> m_lrhr partials (co 5x5, ci-split 2)
__global__ __launch_bounds__(256) void conv3x3_F_k(const float* __restrict chf2,
                                                   const float* __restrict wtE,
                                                   const float* __restrict benc,
                                                   float* __restrict pA,
                                                   float* __restrict pB, int N) {
    int t = blockIdx.x;
    int pxb = t % 32; t /= 32;
    int n = t % N; t /= N;
    int g = t % 5;
    int s = t / 5;
    conv3x3_2px<25, 5, 32, 7, WH, WH, 32>(chf2, wtE, benc, s ? pB : pA, n, g,
                                          pxb * 256 + (int)threadIdx.x, s * 32, s == 0);
}

// ------- stage D+E: chf2 = 2*chf - carafe(chf, norm(m_hrhr), k=3, up=1), 8 ch-groups -------
__global__ void fuse_de_k(const float* __restrict chf, const float* __restrict mA,
                          const float* __restrict mB, float* __restrict chf2, int N) {
    int b = blockIdx.x;
    int pxb = b % 64;
    int n = (b / 64) % N;
    int c0 = (b / (64 * N)) * 8;
    int px = pxb * 256 + threadIdx.x;
    int yy = px >> 7, xx = px & 127;
    float m[9];
    normalize_mask2<3>(mA + (size_t)n * 9 * HWH + px, mB + (size_t)n * 9 * HWH + px, HWH, m);
    int offs[9];
    float mm[9];
#pragma unroll
    for (int t = 0; t < 9; t++) {
        int sy = yy + t / 3 - 1, sx = xx + t % 3 - 1;
        bool ok = (sy >= 0 && sy < WH && sx >= 0 && sx < WH);
        offs[t] = ok ? sy * WH + sx : 0;
        mm[t] = ok ? m[t] : 0.f;
    }
    const float* cb = chf + (size_t)n * 64 * HWH;
    float* ob = chf2 + (size_t)n * 64 * HWH + px;
#pragma unroll
    for (int c = c0; c < c0 + 8; c++) {
        const float* xc = cb + (size_t)c * HWH;
        float s = 0.f, center = 0.f;
#pragma unroll
        for (int t = 0; t < 9; t++) {
            float xv = xc[offs[t]];
            if (t == 4) center = xv;
            s = fmaf(mm[t], xv, s);
        }
        ob[(size_t)c * HWH] = 2.f * center - s;
    }
}

// ---- stage H+I: mask_lr = (m_lrhr) + carafe(g_out, norm(m_lrhr), k=5, up=2) ----
__global__ void fuse_hi_k(const float* __restrict mA, const float* __restrict mB,
                          const float* __restrict g, float* __restrict mask_lr, int N) {
    int b = blockIdx.x;
    int pxb = b % 64;
    int n = (b / 64) % N;
    int co0 = (b / (64 * N)) * 5;
    int px = pxb * 256 + threadIdx.x;
    int Y = px >> 7, X = px & 127;
    int h = Y >> 1, w = X >> 1;
    const float* mbA = mA + (size_t)n * 25 * HWH + px;
    const float* mbB = mB + (size_t)n * 25 * HWH + px;
    float m[25];
    normalize_mask2<5>(mbA, mbB, HWH, m);
    float acc[5];
#pragma unroll
    for (int j = 0; j < 5; j++) acc[j] = 0.f;
    const float* gb = g + ((size_t)n * 25 + co0) * HWL;
    for (int k = 0; k < 25; k++) {
        int sy = h + k / 5 - 2, sx = w + k % 5 - 2;
        if (sy >= 0 && sy < WL && sx >= 0 && sx < WL) {
            int off = sy * WL + sx;
            float mk = m[k];
#pragma unroll
            for (int j = 0; j < 5; j++)
                acc[j] = fmaf(mk, gb[(size_t)j * HWL + off], acc[j]);
        }
    }
#pragma unroll
    for (int j = 0; j < 5; j++)
        mask_lr[((size_t)(n * 25 + co0 + j)) * HWH + px] =
            mbA[(size_t)(co0 + j) * HWH] + mbB[(size_t)(co0 + j) * HWH] + acc[j];
}

// ---------------- normalize mask_lr -> out0; 64-thr blocks ----------------
__global__ void norm25_k(const float* __restrict mask_lr, float* __restrict out0, int N) {
    int b = blockIdx.x;
    int pxb = b % 256;
    int n = b / 256;
    int px = pxb * 64 + threadIdx.x;
    float m[25];
    normalize_mask<5>(mask_lr + (size_t)n * 25 * HWH + px, HWH, m);
#pragma unroll
    for (int k = 0; k < 25; k++) out0[((size_t)(n * 25 + k)) * HWH + px] = m[k];
}

// ---- stage L: mask_hr = (m_hrhr) + carafe(k_out, out0, k=5, up=2); 3 co-groups of 3 ----
__global__ void fuse_l_k(const float* __restrict m_n, const float* __restrict kf,
                         const float* __restrict mhA, const float* __restrict mhB,
                         float* __restrict mask_hr, int N) {
    int b = blockIdx.x;
    int pxb = b % 64;
    int n = (b / 64) % N;
    int co0 = (b / (64 * N)) * 3;
    int px = pxb * 256 + threadIdx.x;
    int Y = px >> 7, X = px & 127;
    int h = Y >> 1, w = X >> 1;
    float m[25];
#pragma unroll
    for (int k = 0; k < 25; k++) m[k] = m_n[((size_t)(n * 25 + k)) * HWH + px];
    float acc[3];
#pragma unroll
    for (int j = 0; j < 3; j++) acc[j] = 0.f;
    const float* kb = kf + ((size_t)n * 9 + co0) * HWL;
    for (int k = 0; k < 25; k++) {
        int sy = h + k / 5 - 2, sx = w + k % 5 - 2;
        if (sy >= 0 && sy < WL && sx >= 0 && sx < WL) {
            int off = sy * WL + sx;
            float mk = m[k];
#pragma unroll
            for (int j = 0; j < 3; j++)
                acc[j] = fmaf(mk, kb[(size_t)j * HWL + off], acc[j]);
        }
    }
#pragma unroll
    for (int j = 0; j < 3; j++)
        mask_hr[((size_t)(n * 9 + co0 + j)) * HWH + px] =
            mhA[((size_t)(n * 9 + co0 + j)) * HWH + px] +
            mhB[((size_t)(n * 9 + co0 + j)) * HWH + px] + acc[j];
}

// ------------- hr_out = 2*hr - carafe(hr, norm(mask_hr), k=3, up=1) -> O1 -------------
#define HRCHG 8
__global__ __launch_bounds__(256) void hr_out_k(const float* __restrict mask_hr,
                                                const float* __restrict hr,
                                                float* __restrict out1, int N) {
    __shared__ float tile[HRCHG][10][132];  // 42240 B
    int b = blockIdx.x;
    int yt = b & 15;
    int g = (b >> 4) & 31;
    int n = b >> 9;
    int y0 = yt * 8;
    int c0 = g * HRCHG;
    const float* hb = hr + ((size_t)n * 256 + c0) * HWH;
    for (int e = threadIdx.x; e < HRCHG * 10 * 132; e += 256) {
        int c = e / (10 * 132);
        int rem = e % (10 * 132);
        int r = rem / 132, col = rem % 132;
        int y = y0 + r - 1, x = col - 1;
        float v = 0.f;
        if (y >= 0 && y < WH && x >= 0 && x < WH) v = hb[(size_t)c * HWH + y * WH + x];
        tile[c][r][col] = v;
    }
    __syncthreads();
    float* ob = out1 + ((size_t)n * 256 + c0) * HWH;
#pragma unroll
    for (int i = 0; i < 4; i++) {
        int lp = threadIdx.x + 256 * i;
        int ly = lp >> 7, lx = lp & 127;
        int px = (y0 + ly) * WH + lx;
        float m[9];
        normalize_mask<3>(mask_hr + (size_t)n * 9 * HWH + px, HWH, m);
        for (int c = 0; c < HRCHG; c++) {
            float center = tile[c][ly + 1][lx + 1];
            float s = 0.f;
#pragma unroll
            for (int t = 0; t < 9; t++)
                s = fmaf(m[t], tile[c][ly + t / 3][lx + t % 3], s);
            ob[(size_t)c * HWH + px] = 2.f * center - s;
        }
    }
}

// ------- lr_out = carafe(lr_feat, out0, k=5, up=2) -> O2 (runs LAST) -------
#define LRCHG 16
__global__ __launch_bounds__(256, 1) void lr_out_k(const float* __restrict m_n,
                                                   const float* __restrict lr,
                                                   float* __restrict out2, int N) {
    __shared__ float tile[LRCHG][12][68];  // 52224 B
    int b = blockIdx.x;
    int yt = b & 7;
    int g = (b >> 3) & 15;
    int n = b >> 7;
    int y0 = yt * 16;
    int hbase = y0 >> 1;
    int c0 = g * LRCHG;
    const float* lrb = lr + ((size_t)n * 256 + c0) * HWL;
    for (int e = threadIdx.x; e < LRCHG * 12 * 68; e += 256) {
        int c = e / (12 * 68);
        int rem = e % (12 * 68);
        int r = rem / 68, col = rem % 68;
        int h = hbase + r - 2, w = col - 2;
        float v = 0.f;
        if (h >= 0 && h < WL && w >= 0 && w < WL) v = lrb[(size_t)c * HWL + h * WL + w];
        tile[c][r][col] = v;
    }
    __syncthreads();
    const float* mb = m_n + (size_t)n * 25 * HWH;
    float* ob = out2 + ((size_t)n * 256 + c0) * HWH;
#pragma unroll
    for (int i = 0; i < 2; i++) {
        int q = threadIdx.x + 256 * i;
        int qy = q >> 6, qx = q & 63;
        int Y0 = y0 + 2 * qy;
        int X0 = 2 * qx;
        float2 mk0[25], mk1[25];
#pragma unroll
        for (int k = 0; k < 25; k++) {
            mk0[k] = *(const float2*)(mb + (size_t)k * HWH + Y0 * WH + X0);
            mk1[k] = *(const float2*)(mb + (size_t)k * HWH + (Y0 + 1) * WH + X0);
        }
        for (int c = 0; c < LRCHG; c++) {
            float a00 = 0.f, a01 = 0.f, a10 = 0.f, a11 = 0.f;
#pragma unroll
            for (int k = 0; k < 25; k++) {
                float v = tile[c][qy + k / 5][qx + k % 5];
                a00 = fmaf(mk0[k].x, v, a00);
                a01 = fmaf(mk0[k].y, v, a01);
                a10 = fmaf(mk1[k].x, v, a10);
                a11 = fmaf(mk1[k].y, v, a11);
            }
            float* op = ob + (size_t)c * HWH + (size_t)Y0 * WH + X0;
            *(float2*)op = make_float2(a00, a01);
            *(float2*)(op + WH) = make_float2(a10, a11);
        }
    }
}

extern "C" void kernel_launch(void* const* d_in, const int* in_sizes, int n_in, void* d_out,
                              int out_size, void* d_ws, size_t ws_size, hipStream_t stream) {
    const float* hr = (const float*)d_in[0];
    const float* lr = (const float*)d_in[1];
    const float* Whr = (const float*)d_in[2];
    const float* bhr = (const float*)d_in[3];
    const float* Wlr = (const float*)d_in[4];
    const float* blr = (const float*)d_in[5];
    const float* Wenc = (const float*)d_in[6];
    const float* benc = (const float*)d_in[7];
    const float* Wenc2 = (const float*)d_in[8];
    const float* benc2 = (const float*)d_in[9];
    float* out = (float*)d_out;
    const int B = in_sizes[0] / (256 * HWH);  // 2
    (void)d_ws; (void)ws_size;

    float* out0 = out;                           // B*25*HWH  (final: mask_lr_n)
    float* O1 = out + (size_t)B * 25 * HWH;      // B*256*HWH (final: hr_out)
    float* O2 = O1 + (size_t)B * 256 * HWH;      // B*256*HWH (final: lr_out)

    // --- scratch inside O2 (dead before lr_out_k overwrites O2) ---
    float* wbase = O2;                                // 60416 floats of weights
    float* wt_hr = wbase;
    float* wt_lr = wbase + 16384;
    float* wtE = wbase + 32768;
    float* wtE2 = wbase + 51200;
    float* mask_hr = O2 + 60416;                      // B*9*HWH

    // --- scratch inside O1 (dead before hr_out_k overwrites O1); total 8,044,544 < 8,388,608
    float* chf = O1;                                  // B*64*HWH
    float* chf2 = chf + (size_t)B * 64 * HWH;
    float* clf = chf2 + (size_t)B * 64 * HWH;         // B*64*HWL
    float* m_hrhr_pA = clf + (size_t)B * 64 * HWL;    // B*9*HWH
    float* m_hrhr_pB = m_hrhr_pA + (size_t)B * 9 * HWH;
    float* m_lrhr_pA = m_hrhr_pB + (size_t)B * 9 * HWH;   // B*25*HWH
    float* m_lrhr_pB = m_lrhr_pA + (size_t)B * 25 * HWH;
    float* g_out = m_lrhr_pB + (size_t)B * 25 * HWH;  // B*25*HWL
    float* k_out = g_out + (size_t)B * 25 * HWL;      // B*9*HWL
    float* mask_lr = k_out + (size_t)B * 9 * HWL;     // B*25*HWH

    prep_w_k<<<64, 256, 0, stream>>>(Whr, Wlr, Wenc, Wenc2, wbase);
    // A+B: 1x1 convs as LDS-GEMM (hr: 256*B, lr: 64*B blocks)
    conv1x1_all_k<<<(HWH / 64) * B + (HWL / 64) * B, 256, 0, stream>>>(
        hr, lr, wt_hr, wt_lr, bhr, blr, chf, clf, B);
    // G + K + C merged, 2px/thread (G: 8*B*5, K: 8*B*2, C: 32*B*6)
    conv3x3_CGK_k<<<8 * B * 5 + 8 * B * 2 + 32 * B * 6, 256, 0, stream>>>(
        chf, clf, wtE, wtE2, benc, benc2, m_hrhr_pA, m_hrhr_pB, g_out, k_out, B);
    // D+E: chf2
    fuse_de_k<<<64 * B * 8, 256, 0, stream>>>(chf, m_hrhr_pA, m_hrhr_pB, chf2, B);
    // F: chf2 -> m_lrhr partials, 2px/thread (32*B*10 blocks)
    conv3x3_F_k<<<32 * B * 10, 256, 0, stream>>>(chf2, wtE, benc, m_lrhr_pA, m_lrhr_pB, B);
    // H+I: mask_lr
    fuse_hi_k<<<64 * B * 5, 256, 0, stream>>>(m_lrhr_pA, m_lrhr_pB, g_out, mask_lr, B);
    // J: out0 = normalize(mask_lr)
    norm25_k<<<256 * B, 64, 0, stream>>>(mask_lr, out0, B);
    // L: mask_hr
    fuse_l_k<<<64 * B * 3, 256, 0, stream>>>(out0, k_out, m_hrhr_pA, m_hrhr_pB, mask_hr, B);
    // M+O: hr_out -> O1 (LDS-tiled)
    hr_out_k<<<B * 512, 256, 0, stream>>>(mask_hr, hr, O1, B);
    // N: lr_out -> O2 (LDS-tiled)
    lr_out_k<<<B * 128, 256, 0, stream>>>(out0, lr, O2, B);
}

// Round 9
// 220.843 us; speedup vs baseline: 1.3579x; 1.3115x over previous
//
#include <hip/hip_runtime.h>

// FreqFusion forward, f32. Shapes fixed: B=2, C=256, CC=64, HR=128x128, LR=64x64.
// Scratch: d_ws unused. Intermediates live inside d_out (see layout in kernel_launch).
#define HWH 16384   // 128*128
#define HWL 4096    // 64*64
#define WH 128
#define WL 64

// ---------------- hamming helpers ----------------
__device__ __forceinline__ float ham3v(int t) {
    const float h[3] = {0.08f, 1.0f, 0.08f};
    return h[t / 3] * h[t % 3];
}
__device__ __forceinline__ float ham5v(int t) {
    const float h[5] = {0.08f, 0.54f, 1.0f, 0.54f, 0.08f};
    return h[t / 5] * h[t % 5];
}

// softmax over K*K ch, *ham, renorm  ==  exp(x-max)*ham / sum(exp(x-max)*ham)
template <int K>
__device__ __forceinline__ void normalize_post(float* m) {
    constexpr int K2 = K * K;
    float mx = -1e30f;
#pragma unroll
    for (int k = 0; k < K2; k++) mx = fmaxf(mx, m[k]);
    float s = 0.f;
#pragma unroll
    for (int k = 0; k < K2; k++) {
        float hv = (K == 3) ? ham3v(k) : ham5v(k);
        float e = __expf(m[k] - mx) * hv;
        m[k] = e;
        s += e;
    }
    float inv = 1.f / s;
#pragma unroll
    for (int k = 0; k < K2; k++) m[k] *= inv;
}

template <int K>
__device__ __forceinline__ void normalize_mask(const float* __restrict src, int stride,
                                               float* m) {
#pragma unroll
    for (int k = 0; k < K * K; k++) m[k] = src[(size_t)k * stride];
    normalize_post<K>(m);
}

template <int K>
__device__ __forceinline__ void normalize_mask2(const float* __restrict a,
                                                const float* __restrict b, int stride,
                                                float* m) {
#pragma unroll
    for (int k = 0; k < K * K; k++)
        m[k] = a[(size_t)k * stride] + b[(size_t)k * stride];
    normalize_post<K>(m);
}

// unaligned float4 load (4B-aligned ok; compiler may split)
struct F4 { float x, y, z, w; };
__device__ __forceinline__ F4 ld4u(const float* p) {
    F4 v;
    __builtin_memcpy(&v, p, 16);
    return v;
}

// ---------------- weight prep: transpose to [ci][co] (co contiguous) ----------------
__global__ void prep_w_k(const float* __restrict Whr, const float* __restrict Wlr,
                         const float* __restrict Wenc, const float* __restrict Wenc2,
                         float* __restrict wbase) {
    int tid = blockIdx.x * blockDim.x + threadIdx.x;
    int stride = gridDim.x * blockDim.x;
    float* wt_hr = wbase;
    float* wt_lr = wbase + 16384;
    float* wtE = wbase + 32768;
    float* wtE2 = wbase + 51200;
    for (int i = tid; i < 16384; i += stride) {
        int ci = i >> 6, co = i & 63;
        wt_hr[i] = Whr[co * 256 + ci];
        wt_lr[i] = Wlr[co * 256 + ci];
    }
    for (int i = tid; i < 18432; i += stride) {
        int r = i >> 5, co = i & 31;
        int ci = r / 9, t = r % 9;
        wtE[i] = (co < 25) ? Wenc[(co * 64 + ci) * 9 + t] : 0.f;
    }
    for (int i = tid; i < 9216; i += stride) {
        int r = i >> 4, co = i & 15;
        int ci = r / 9, t = r % 9;
        wtE2[i] = (co < 9) ? Wenc2[(co * 64 + ci) * 9 + t] : 0.f;
    }
}

// ------------- 1x1 conv as LDS-GEMM: stage 128ci x 64px (32KB) x 2 halves -------------
// wave w owns co strip [16w,16w+16); co0 forced to SGPR via readfirstlane so the
// weight reads become s_load (round-8 lesson: tid-derived index -> per-lane VMEM).
__global__ __launch_bounds__(256) void conv1x1_all_k(
    const float* __restrict hr, const float* __restrict lrf, const float* __restrict wt_hr,
    const float* __restrict wt_lr, const float* __restrict bhr, const float* __restrict blr,
    float* __restrict chf, float* __restrict clf, int N) {
    __shared__ float sm[128 * 64];  // 32 KB
    int b = blockIdx.x;
    const int HRB = (HWH / 64) * N;  // 512
    const float *x, *wt, *bias;
    float* y;
    int HWp, n, px0;
    if (b < HRB) {
        x = hr; wt = wt_hr; bias = bhr; y = chf; HWp = HWH;
        n = b / (HWH / 64);
        px0 = (b % (HWH / 64)) * 64;
    } else {
        int b2 = b - HRB;
        x = lrf; wt = wt_lr; bias = blr; y = clf; HWp = HWL;
        n = b2 / (HWL / 64);
        px0 = (b2 % (HWL / 64)) * 64;
    }
    const float* xb = x + (size_t)n * 256 * HWp + px0;
    int pl = threadIdx.x & 63;
    int co0 = __builtin_amdgcn_readfirstlane((int)(threadIdx.x >> 6)) * 16;  // SGPR
    float acc[16];
#pragma unroll
    for (int j = 0; j < 16; j++) acc[j] = 0.f;
    const float* w0 = wt + co0;  // uniform -> s_load weights
#pragma unroll
    for (int half = 0; half < 2; half++) {
        __syncthreads();
        for (int e = threadIdx.x; e < 2048; e += 256) {
            int ci = e >> 4, q = e & 15;
            *reinterpret_cast<float4*>(sm + ci * 64 + q * 4) =
                *reinterpret_cast<const float4*>(xb + (size_t)(half * 128 + ci) * HWp + q * 4);
        }
        __syncthreads();
        const float* wh = w0 + (half * 128) * 64;
#pragma unroll 8
        for (int ci = 0; ci < 128; ci++) {
            float xv = sm[ci * 64 + pl];
            const float* wr = wh + ci * 64;  // uniform
#pragma unroll
            for (int j = 0; j < 16; j++) acc[j] = fmaf(wr[j], xv, acc[j]);
        }
    }
    float* yb = y + ((size_t)(n * 64 + co0)) * HWp + px0 + pl;
#pragma unroll
    for (int j = 0; j < 16; j++) yb[(size_t)j * HWp] = acc[j] + bias[co0 + j];
}

// ------------- 3x3 conv, 2px/thread: 3 float4 row-loads -> 18*CH FMA per ci -------------
template <int COUT, int CH, int PAD, int LOG2W, int HH, int WW, int NCI>
__device__ __forceinline__ void conv3x3_2px(const float* __restrict x,
                                            const float* __restrict wt,
                                            const float* __restrict bias,
                                            float* __restrict y, int n, int g, int pxh,
                                            int ci0, bool addb) {
    constexpr int HWp = HH * WW;
    int px = pxh * 2;
    int yy = px >> LOG2W, xx = px & (WW - 1);
    int co0 = g * CH;  // uniform
    float a0[CH], a1[CH];
#pragma unroll
    for (int j = 0; j < CH; j++) { a0[j] = 0.f; a1[j] = 0.f; }
    const float* xb = x + (size_t)(n * 64 + ci0) * HWp;
    const float* wb0 = wt + (size_t)ci0 * 9 * PAD + co0;
    int roff[3];
    bool rv[3];
#pragma unroll
    for (int r = 0; r < 3; r++) {
        int sy = yy + r - 1;
        rv[r] = (sy >= 0) && (sy < HH);
        roff[r] = sy * WW + xx - 1;
    }
    bool lv = (xx > 0), rgv = (xx < WW - 2);
    for (int ci = 0; ci < NCI; ci++) {
        const float* xc = xb + (size_t)ci * HWp;
        const float* w = wb0 + (size_t)ci * 9 * PAD;
#pragma unroll
        for (int r = 0; r < 3; r++) {
            F4 v = ld4u(xc + roff[r]);  // stays inside d_out; masked below
            float t0 = (rv[r] && lv) ? v.x : 0.f;
            float t1 = rv[r] ? v.y : 0.f;
            float t2 = rv[r] ? v.z : 0.f;
            float t3 = (rv[r] && rgv) ? v.w : 0.f;
#pragma unroll
            for (int j = 0; j < CH; j++) {
                float w0 = w[(r * 3 + 0) * PAD + j];
                float w1 = w[(r * 3 + 1) * PAD + j];
                float w2 = w[(r * 3 + 2) * PAD + j];
                a0[j] = fmaf(w0, t0, fmaf(w1, t1, fmaf(w2, t2, a0[j])));
                a1[j] = fmaf(w0, t1, fmaf(w1, t2, fmaf(w2, t3, a1[j])));
            }
        }
    }
#pragma unroll
    for (int j = 0; j < CH; j++) {
        int co = co0 + j;
        if (co < COUT) {
            float bv = addb ? bias[co] : 0.f;
            float* op = y + ((size_t)(n * COUT + co)) * HWp + px;
            *reinterpret_cast<float2*>(op) = make_float2(a0[j] + bv, a1[j] + bv);
        }
    }
}

// merged: G (clf->g_out, co5x5), K (clf->k_out, co2x5), C (chf->m_hrhr partials, co3x3, ci2)
__global__ __launch_bounds__(256) void conv3x3_CGK_k(
    const float* __restrict chf, const float* __restrict clf, const float* __restrict wtE,
    const float* __restrict wtE2, const float* __restrict benc,
    const float* __restrict benc2, float* __restrict m_hrhr_pA, float* __restrict m_hrhr_pB,
    float* __restrict g_out, float* __restrict k_out, int N) {
    const int GB = 8 * N * 5, KB = 8 * N * 2;
    int b = blockIdx.x;
    if (b < GB) {
        int pxb = b % 8;
        int n = (b / 8) % N;
        int g = b / (8 * N);
        conv3x3_2px<25, 5, 32, 6, WL, WL, 64>(clf, wtE, benc, g_out, n, g,
                                              pxb * 256 + (int)threadIdx.x, 0, true);
    } else if (b < GB + KB) {
        int t = b - GB;
        int pxb = t % 8;
        int n = (t / 8) % N;
        int g = t / (8 * N);
        conv3x3_2px<9, 5, 16, 6, WL, WL, 64>(clf, wtE2, benc2, k_out, n, g,
                                             pxb * 256 + (int)threadIdx.x, 0, true);
    } else {
        int t = b - GB - KB;
        int pxb = t % 32; t /= 32;
        int n = t % N; t /= N;
        int g = t % 3;
        int s = t / 3;
        conv3x3_2px<9, 3, 16, 7, WH, WH, 32>(chf, wtE2, benc2, s ? m_hrhr_pB : m_hrhr_pA,
                                             n, g, pxb * 256 + (int)threadIdx.x, s * 32,
                                             s == 0);
    }
}

// F: chf2 -> m_lrhr partials (co 5x5, ci-split 2)
__global__ __launch_bounds__(256) void conv3x3_F_k(const float* __restrict chf2,
                                                   const float* __restrict wtE,
                                                   const float* __restrict benc,
                                                   float* __restrict pA,
                                                   float* __restrict pB, int N) {
    int t = blockIdx.x;
    int pxb = t % 32; t /= 32;
    int n = t % N; t /= N;
    int g = t % 5;
    int s = t / 5;
    conv3x3_2px<25, 5, 32, 7, WH, WH, 32>(chf2, wtE, benc, s ? pB : pA, n, g,
                                          pxb * 256 + (int)threadIdx.x, s * 32, s == 0);
}

// ------- stage D+E: chf2 = 2*chf - carafe(chf, norm(m_hrhr), k=3, up=1), 8 ch-groups -------
__global__ void fuse_de_k(const float* __restrict chf, const float* __restrict mA,
                          const float* __restrict mB, float* __restrict chf2, int N) {
    int b = blockIdx.x;
    int pxb = b % 64;
    int n = (b / 64) % N;
    int c0 = (b / (64 * N)) * 8;
    int px = pxb * 256 + threadIdx.x;
    int yy = px >> 7, xx = px & 127;
    float m[9];
    normalize_mask2<3>(mA + (size_t)n * 9 * HWH + px, mB + (size_t)n * 9 * HWH + px, HWH, m);
    int offs[9];
    float mm[9];
#pragma unroll
    for (int t = 0; t < 9; t++) {
        int sy = yy + t / 3 - 1, sx = xx + t % 3 - 1;
        bool ok = (sy >= 0 && sy < WH && sx >= 0 && sx < WH);
        offs[t] = ok ? sy * WH + sx : 0;
        mm[t] = ok ? m[t] : 0.f;
    }
    const float* cb = chf + (size_t)n * 64 * HWH;
    float* ob = chf2 + (size_t)n * 64 * HWH + px;
#pragma unroll
    for (int c = c0; c < c0 + 8; c++) {
        const float* xc = cb + (size_t)c * HWH;
        float s = 0.f, center = 0.f;
#pragma unroll
        for (int t = 0; t < 9; t++) {
            float xv = xc[offs[t]];
            if (t == 4) center = xv;
            s = fmaf(mm[t], xv, s);
        }
        ob[(size_t)c * HWH] = 2.f * center - s;
    }
}

// ---- stage H+I: mask_lr = (m_lrhr) + carafe(g_out, norm(m_lrhr), k=5, up=2) ----
__global__ void fuse_hi_k(const float* __restrict mA, const float* __restrict mB,
                          const float* __restrict g, float* __restrict mask_lr, int N) {
    int b = blockIdx.x;
    int pxb = b % 64;
    int n = (b / 64) % N;
    int co0 = (b / (64 * N)) * 5;
    int px = pxb * 256 + threadIdx.x;
    int Y = px >> 7, X = px & 127;
    int h = Y >> 1, w = X >> 1;
    const float* mbA = mA + (size_t)n * 25 * HWH + px;
    const float* mbB = mB + (size_t)n * 25 * HWH + px;
    float m[25];
    normalize_mask2<5>(mbA, mbB, HWH, m);
    float acc[5];
#pragma unroll
    for (int j = 0; j < 5; j++) acc[j] = 0.f;
    const float* gb = g + ((size_t)n * 25 + co0) * HWL;
    for (int k = 0; k < 25; k++) {
        int sy = h + k / 5 - 2, sx = w + k % 5 - 2;
        if (sy >= 0 && sy < WL && sx >= 0 && sx < WL) {
            int off = sy * WL + sx;
            float mk = m[k];
#pragma unroll
            for (int j = 0; j < 5; j++)
                acc[j] = fmaf(mk, gb[(size_t)j * HWL + off], acc[j]);
        }
    }
#pragma unroll
    for (int j = 0; j < 5; j++)
        mask_lr[((size_t)(n * 25 + co0 + j)) * HWH + px] =
            mbA[(size_t)(co0 + j) * HWH] + mbB[(size_t)(co0 + j) * HWH] + acc[j];
}

// ---------------- normalize mask_lr -> out0; 64-thr blocks ----------------
__global__ void norm25_k(const float* __restrict mask_lr, float* __restrict out0, int N) {
    int b = blockIdx.x;
    int pxb = b % 256;
    int n = b / 256;
    int px = pxb * 64 + threadIdx.x;
    float m[25];
    normalize_mask<5>(mask_lr + (size_t)n * 25 * HWH + px, HWH, m);
#pragma unroll
    for (int k = 0; k < 25; k++) out0[((size_t)(n * 25 + k)) * HWH + px] = m[k];
}

// ---- stage L: mask_hr = (m_hrhr) + carafe(k_out, out0, k=5, up=2); 3 co-groups of 3 ----
__global__ void fuse_l_k(const float* __restrict m_n, const float* __restrict kf,
                         const float* __restrict mhA, const float* __restrict mhB,
                         float* __restrict mask_hr, int N) {
    int b = blockIdx.x;
    int pxb = b % 64;
    int n = (b / 64) % N;
    int co0 = (b / (64 * N)) * 3;
    int px = pxb * 256 + threadIdx.x;
    int Y = px >> 7, X = px & 127;
    int h = Y >> 1, w = X >> 1;
    float m[25];
#pragma unroll
    for (int k = 0; k < 25; k++) m[k] = m_n[((size_t)(n * 25 + k)) * HWH + px];
    float acc[3];
#pragma unroll
    for (int j = 0; j < 3; j++) acc[j] = 0.f;
    const float* kb = kf + ((size_t)n * 9 + co0) * HWL;
    for (int k = 0; k < 25; k++) {
        int sy = h + k / 5 - 2, sx = w + k % 5 - 2;
        if (sy >= 0 && sy < WL && sx >= 0 && sx < WL) {
            int off = sy * WL + sx;
            float mk = m[k];
#pragma unroll
            for (int j = 0; j < 3; j++)
                acc[j] = fmaf(mk, kb[(size_t)j * HWL + off], acc[j]);
        }
    }
#pragma unroll
    for (int j = 0; j < 3; j++)
        mask_hr[((size_t)(n * 9 + co0 + j)) * HWH + px] =
            mhA[((size_t)(n * 9 + co0 + j)) * HWH + px] +
            mhB[((size_t)(n * 9 + co0 + j)) * HWH + px] + acc[j];
}

// ------------- hr_out = 2*hr - carafe(hr, norm(mask_hr), k=3, up=1) -> O1 -------------
#define HRCHG 8
__global__ __launch_bounds__(256) void hr_out_k(const float* __restrict mask_hr,
                                                const float* __restrict hr,
                                                float* __restrict out1, int N) {
    __shared__ float tile[HRCHG][10][132];  // 42240 B
    int b = blockIdx.x;
    int yt = b & 15;
    int g = (b >> 4) & 31;
    int n = b >> 9;
    int y0 = yt * 8;
    int c0 = g * HRCHG;
    const float* hb = hr + ((size_t)n * 256 + c0) * HWH;
    for (int e = threadIdx.x; e < HRCHG * 10 * 132; e += 256) {
        int c = e / (10 * 132);
        int rem = e % (10 * 132);
        int r = rem / 132, col = rem % 132;
        int y = y0 + r - 1, x = col - 1;
        float v = 0.f;
        if (y >= 0 && y < WH && x >= 0 && x < WH) v = hb[(size_t)c * HWH + y * WH + x];
        tile[c][r][col] = v;
    }
    __syncthreads();
    float* ob = out1 + ((size_t)n * 256 + c0) * HWH;
#pragma unroll
    for (int i = 0; i < 4; i++) {
        int lp = threadIdx.x + 256 * i;
        int ly = lp >> 7, lx = lp & 127;
        int px = (y0 + ly) * WH + lx;
        float m[9];
        normalize_mask<3>(mask_hr + (size_t)n * 9 * HWH + px, HWH, m);
        for (int c = 0; c < HRCHG; c++) {
            float center = tile[c][ly + 1][lx + 1];
            float s = 0.f;
#pragma unroll
            for (int t = 0; t < 9; t++)
                s = fmaf(m[t], tile[c][ly + t / 3][lx + t % 3], s);
            ob[(size_t)c * HWH + px] = 2.f * center - s;
        }
    }
}

// ------- lr_out = carafe(lr_feat, out0, k=5, up=2) -> O2 (runs LAST) -------
#define LRCHG 16
__global__ __launch_bounds__(256, 1) void lr_out_k(const float* __restrict m_n,
                                                   const float* __restrict lr,
                                                   float* __restrict out2, int N) {
    __shared__ float tile[LRCHG][12][68];  // 52224 B
    int b = blockIdx.x;
    int yt = b & 7;
    int g = (b >> 3) & 15;
    int n = b >> 7;
    int y0 = yt * 16;
    int hbase = y0 >> 1;
    int c0 = g * LRCHG;
    const float* lrb = lr + ((size_t)n * 256 + c0) * HWL;
    for (int e = threadIdx.x; e < LRCHG * 12 * 68; e += 256) {
        int c = e / (12 * 68);
        int rem = e % (12 * 68);
        int r = rem / 68, col = rem % 68;
        int h = hbase + r - 2, w = col - 2;
        float v = 0.f;
        if (h >= 0 && h < WL && w >= 0 && w < WL) v = lrb[(size_t)c * HWL + h * WL + w];
        tile[c][r][col] = v;
    }
    __syncthreads();
    const float* mb = m_n + (size_t)n * 25 * HWH;
    float* ob = out2 + ((size_t)n * 256 + c0) * HWH;
#pragma unroll
    for (int i = 0; i < 2; i++) {
        int q = threadIdx.x + 256 * i;
        int qy = q >> 6, qx = q & 63;
        int Y0 = y0 + 2 * qy;
        int X0 = 2 * qx;
        float2 mk0[25], mk1[25];
#pragma unroll
        for (int k = 0; k < 25; k++) {
            mk0[k] = *(const float2*)(mb + (size_t)k * HWH + Y0 * WH + X0);
            mk1[k] = *(const float2*)(mb + (size_t)k * HWH + (Y0 + 1) * WH + X0);
        }
        for (int c = 0; c < LRCHG; c++) {
            float a00 = 0.f, a01 = 0.f, a10 = 0.f, a11 = 0.f;
#pragma unroll
            for (int k = 0; k < 25; k++) {
                float v = tile[c][qy + k / 5][qx + k % 5];
                a00 = fmaf(mk0[k].x, v, a00);
                a01 = fmaf(mk0[k].y, v, a01);
                a10 = fmaf(mk1[k].x, v, a10);
                a11 = fmaf(mk1[k].y, v, a11);
            }
            float* op = ob + (size_t)c * HWH + (size_t)Y0 * WH + X0;
            *(float2*)op = make_float2(a00, a01);
            *(float2*)(op + WH) = make_float2(a10, a11);
        }
    }
}

extern "C" void kernel_launch(void* const* d_in, const int* in_sizes, int n_in, void* d_out,
                              int out_size, void* d_ws, size_t ws_size, hipStream_t stream) {
    const float* hr = (const float*)d_in[0];
    const float* lr = (const float*)d_in[1];
    const float* Whr = (const float*)d_in[2];
    const float* bhr = (const float*)d_in[3];
    const float* Wlr = (const float*)d_in[4];
    const float* blr = (const float*)d_in[5];
    const float* Wenc = (const float*)d_in[6];
    const float* benc = (const float*)d_in[7];
    const float* Wenc2 = (const float*)d_in[8];
    const float* benc2 = (const float*)d_in[9];
    float* out = (float*)d_out;
    const int B = in_sizes[0] / (256 * HWH);  // 2
    (void)d_ws; (void)ws_size;

    float* out0 = out;                           // B*25*HWH  (final: mask_lr_n)
    float* O1 = out + (size_t)B * 25 * HWH;      // B*256*HWH (final: hr_out)
    float* O2 = O1 + (size_t)B * 256 * HWH;      // B*256*HWH (final: lr_out)

    // --- scratch inside O2 (dead before lr_out_k overwrites O2) ---
    float* wbase = O2;                                // 60416 floats of weights
    float* wt_hr = wbase;
    float* wt_lr = wbase + 16384;
    float* wtE = wbase + 32768;
    float* wtE2 = wbase + 51200;
    float* mask_hr = O2 + 60416;                      // B*9*HWH

    // --- scratch inside O1 (dead before hr_out_k overwrites O1); total 8,044,544 < 8,388,608
    float* chf = O1;                                  // B*64*HWH
    float* chf2 = chf + (size_t)B * 64 * HWH;
    float* clf = chf2 + (size_t)B * 64 * HWH;         // B*64*HWL
    float* m_hrhr_pA = clf + (size_t)B * 64 * HWL;    // B*9*HWH
    float* m_hrhr_pB = m_hrhr_pA + (size_t)B * 9 * HWH;
    float* m_lrhr_pA = m_hrhr_pB + (size_t)B * 9 * HWH;   // B*25*HWH
    float* m_lrhr_pB = m_lrhr_pA + (size_t)B * 25 * HWH;
    float* g_out = m_lrhr_pB + (size_t)B * 25 * HWH;  // B*25*HWL
    float* k_out = g_out + (size_t)B * 25 * HWL;      // B*9*HWL
    float* mask_lr = k_out + (size_t)B * 9 * HWL;     // B*25*HWH

    prep_w_k<<<64, 256, 0, stream>>>(Whr, Wlr, Wenc, Wenc2, wbase);
    // A+B: 1x1 convs as LDS-GEMM, scalarized weights (hr: 512, lr: 128 blocks)
    conv1x1_all_k<<<(HWH / 64) * B + (HWL / 64) * B, 256, 0, stream>>>(
        hr, lr, wt_hr, wt_lr, bhr, blr, chf, clf, B);
    // G + K + C merged, 2px/thread (G: 8*B*5, K: 8*B*2, C: 32*B*6)
    conv3x3_CGK_k<<<8 * B * 5 + 8 * B * 2 + 32 * B * 6, 256, 0, stream>>>(
        chf, clf, wtE, wtE2, benc, benc2, m_hrhr_pA, m_hrhr_pB, g_out, k_out, B);
    // D+E: chf2
    fuse_de_k<<<64 * B * 8, 256, 0, stream>>>(chf, m_hrhr_pA, m_hrhr_pB, chf2, B);
    // F: chf2 -> m_lrhr partials, 2px/thread (32*B*10 blocks)
    conv3x3_F_k<<<32 * B * 10, 256, 0, stream>>>(chf2, wtE, benc, m_lrhr_pA, m_lrhr_pB, B);
    // H+I: mask_lr
    fuse_hi_k<<<64 * B * 5, 256, 0, stream>>>(m_lrhr_pA, m_lrhr_pB, g_out, mask_lr, B);
    // J: out0 = normalize(mask_lr)
    norm25_k<<<256 * B, 64, 0, stream>>>(mask_lr, out0, B);
    // L: mask_hr
    fuse_l_k<<<64 * B * 3, 256, 0, stream>>>(out0, k_out, m_hrhr_pA, m_hrhr_pB, mask_hr, B);
    // M+O: hr_out -> O1 (LDS-tiled)
    hr_out_k<<<B * 512, 256, 0, stream>>>(mask_hr, hr, O1, B);
    // N: lr_out -> O2 (LDS-tiled)
    lr_out_k<<<B * 128, 256, 0, stream>>>(out0, lr, O2, B);
}

// Round 10
// 186.750 us; speedup vs baseline: 1.6057x; 1.1826x over previous
//
#include <hip/hip_runtime.h>

// FreqFusion forward, f32. Shapes fixed: B=2, C=256, CC=64, HR=128x128, LR=64x64.
// Scratch: d_ws unused. Intermediates live inside d_out (see layout in kernel_launch).
#define HWH 16384   // 128*128
#define HWL 4096    // 64*64
#define WH 128
#define WL 64

// ---------------- hamming helpers ----------------
__device__ __forceinline__ float ham3v(int t) {
    const float h[3] = {0.08f, 1.0f, 0.08f};
    return h[t / 3] * h[t % 3];
}
__device__ __forceinline__ float ham5v(int t) {
    const float h[5] = {0.08f, 0.54f, 1.0f, 0.54f, 0.08f};
    return h[t / 5] * h[t % 5];
}

// softmax over K*K ch, *ham, renorm  ==  exp(x-max)*ham / sum(exp(x-max)*ham)
template <int K>
__device__ __forceinline__ void normalize_post(float* m) {
    constexpr int K2 = K * K;
    float mx = -1e30f;
#pragma unroll
    for (int k = 0; k < K2; k++) mx = fmaxf(mx, m[k]);
    float s = 0.f;
#pragma unroll
    for (int k = 0; k < K2; k++) {
        float hv = (K == 3) ? ham3v(k) : ham5v(k);
        float e = __expf(m[k] - mx) * hv;
        m[k] = e;
        s += e;
    }
    float inv = 1.f / s;
#pragma unroll
    for (int k = 0; k < K2; k++) m[k] *= inv;
}

template <int K>
__device__ __forceinline__ void normalize_mask(const float* __restrict src, int stride,
                                               float* m) {
#pragma unroll
    for (int k = 0; k < K * K; k++) m[k] = src[(size_t)k * stride];
    normalize_post<K>(m);
}

template <int K>
__device__ __forceinline__ void normalize_mask2(const float* __restrict a,
                                                const float* __restrict b, int stride,
                                                float* m) {
#pragma unroll
    for (int k = 0; k < K * K; k++)
        m[k] = a[(size_t)k * stride] + b[(size_t)k * stride];
    normalize_post<K>(m);
}

// unaligned float4 load (4B-aligned ok; compiler may split)
struct F4 { float x, y, z, w; };
__device__ __forceinline__ F4 ld4u(const float* p) {
    F4 v;
    __builtin_memcpy(&v, p, 16);
    return v;
}

// ---------------- weight prep: transpose to [ci][co] (co contiguous) ----------------
__global__ void prep_w_k(const float* __restrict Whr, const float* __restrict Wlr,
                         const float* __restrict Wenc, const float* __restrict Wenc2,
                         float* __restrict wbase) {
    int tid = blockIdx.x * blockDim.x + threadIdx.x;
    int stride = gridDim.x * blockDim.x;
    float* wt_hr = wbase;
    float* wt_lr = wbase + 16384;
    float* wtE = wbase + 32768;
    float* wtE2 = wbase + 51200;
    for (int i = tid; i < 16384; i += stride) {
        int ci = i >> 6, co = i & 63;
        wt_hr[i] = Whr[co * 256 + ci];
        wt_lr[i] = Wlr[co * 256 + ci];
    }
    for (int i = tid; i < 18432; i += stride) {
        int r = i >> 5, co = i & 31;
        int ci = r / 9, t = r % 9;
        wtE[i] = (co < 25) ? Wenc[(co * 64 + ci) * 9 + t] : 0.f;
    }
    for (int i = tid; i < 9216; i += stride) {
        int r = i >> 4, co = i & 15;
        int ci = r / 9, t = r % 9;
        wtE2[i] = (co < 9) ? Wenc2[(co * 64 + ci) * 9 + t] : 0.f;
    }
}

// ------------- 1x1 conv as LDS-GEMM: stage 128ci x 64px (32KB) x 2 halves -------------
__global__ __launch_bounds__(256) void conv1x1_all_k(
    const float* __restrict hr, const float* __restrict lrf, const float* __restrict wt_hr,
    const float* __restrict wt_lr, const float* __restrict bhr, const float* __restrict blr,
    float* __restrict chf, float* __restrict clf, int N) {
    __shared__ float sm[128 * 64];  // 32 KB
    int b = blockIdx.x;
    const int HRB = (HWH / 64) * N;  // 512
    const float *x, *wt, *bias;
    float* y;
    int HWp, n, px0;
    if (b < HRB) {
        x = hr; wt = wt_hr; bias = bhr; y = chf; HWp = HWH;
        n = b / (HWH / 64);
        px0 = (b % (HWH / 64)) * 64;
    } else {
        int b2 = b - HRB;
        x = lrf; wt = wt_lr; bias = blr; y = clf; HWp = HWL;
        n = b2 / (HWL / 64);
        px0 = (b2 % (HWL / 64)) * 64;
    }
    const float* xb = x + (size_t)n * 256 * HWp + px0;
    int pl = threadIdx.x & 63;
    int co0 = __builtin_amdgcn_readfirstlane((int)(threadIdx.x >> 6)) * 16;  // SGPR
    float acc[16];
#pragma unroll
    for (int j = 0; j < 16; j++) acc[j] = 0.f;
    const float* w0 = wt + co0;  // uniform -> s_load weights
#pragma unroll
    for (int half = 0; half < 2; half++) {
        __syncthreads();
        for (int e = threadIdx.x; e < 2048; e += 256) {
            int ci = e >> 4, q = e & 15;
            *reinterpret_cast<float4*>(sm + ci * 64 + q * 4) =
                *reinterpret_cast<const float4*>(xb + (size_t)(half * 128 + ci) * HWp + q * 4);
        }
        __syncthreads();
        const float* wh = w0 + (half * 128) * 64;
#pragma unroll 8
        for (int ci = 0; ci < 128; ci++) {
            float xv = sm[ci * 64 + pl];
            const float* wr = wh + ci * 64;  // uniform
#pragma unroll
            for (int j = 0; j < 16; j++) acc[j] = fmaf(wr[j], xv, acc[j]);
        }
    }
    float* yb = y + ((size_t)(n * 64 + co0)) * HWp + px0 + pl;
#pragma unroll
    for (int j = 0; j < 16; j++) yb[(size_t)j * HWp] = acc[j] + bias[co0 + j];
}

// ------------- 3x3 conv, 2px/thread: 3 float4 row-loads -> 18*CH FMA per ci -------------
template <int COUT, int CH, int PAD, int LOG2W, int HH, int WW, int NCI>
__device__ __forceinline__ void conv3x3_2px(const float* __restrict x,
                                            const float* __restrict wt,
                                            const float* __restrict bias,
                                            float* __restrict y, int n, int g, int pxh,
                                            int ci0, bool addb) {
    constexpr int HWp = HH * WW;
    int px = pxh * 2;
    int yy = px >> LOG2W, xx = px & (WW - 1);
    int co0 = g * CH;  // uniform
    float a0[CH], a1[CH];
#pragma unroll
    for (int j = 0; j < CH; j++) { a0[j] = 0.f; a1[j] = 0.f; }
    const float* xb = x + (size_t)(n * 64 + ci0) * HWp;
    const float* wb0 = wt + (size_t)ci0 * 9 * PAD + co0;
    int roff[3];
    bool rv[3];
#pragma unroll
    for (int r = 0; r < 3; r++) {
        int sy = yy + r - 1;
        rv[r] = (sy >= 0) && (sy < HH);
        roff[r] = sy * WW + xx - 1;
    }
    bool lv = (xx > 0), rgv = (xx < WW - 2);
    for (int ci = 0; ci < NCI; ci++) {
        const float* xc = xb + (size_t)ci * HWp;
        const float* w = wb0 + (size_t)ci * 9 * PAD;
#pragma unroll
        for (int r = 0; r < 3; r++) {
            F4 v = ld4u(xc + roff[r]);  // stays inside d_out; masked below
            float t0 = (rv[r] && lv) ? v.x : 0.f;
            float t1 = rv[r] ? v.y : 0.f;
            float t2 = rv[r] ? v.z : 0.f;
            float t3 = (rv[r] && rgv) ? v.w : 0.f;
#pragma unroll
            for (int j = 0; j < CH; j++) {
                float w0 = w[(r * 3 + 0) * PAD + j];
                float w1 = w[(r * 3 + 1) * PAD + j];
                float w2 = w[(r * 3 + 2) * PAD + j];
                a0[j] = fmaf(w0, t0, fmaf(w1, t1, fmaf(w2, t2, a0[j])));
                a1[j] = fmaf(w0, t1, fmaf(w1, t2, fmaf(w2, t3, a1[j])));
            }
        }
    }
#pragma unroll
    for (int j = 0; j < CH; j++) {
        int co = co0 + j;
        if (co < COUT) {
            float bv = addb ? bias[co] : 0.f;
            float* op = y + ((size_t)(n * COUT + co)) * HWp + px;
            *reinterpret_cast<float2*>(op) = make_float2(a0[j] + bv, a1[j] + bv);
        }
    }
}

// merged: G (clf->g_out, co5x5), K (clf->k_out, co2x5), C (chf->m_hrhr partials, co3x3, ci2)
__global__ __launch_bounds__(256) void conv3x3_CGK_k(
    const float* __restrict chf, const float* __restrict clf, const float* __restrict wtE,
    const float* __restrict wtE2, const float* __restrict benc,
    const float* __restrict benc2, float* __restrict m_hrhr_pA, float* __restrict m_hrhr_pB,
    float* __restrict g_out, float* __restrict k_out, int N) {
    const int GB = 8 * N * 5, KB = 8 * N * 2;
    int b = blockIdx.x;
    if (b < GB) {
        int pxb = b % 8;
        int n = (b / 8) % N;
        int g = b / (8 * N);
        conv3x3_2px<25, 5, 32, 6, WL, WL, 64>(clf, wtE, benc, g_out, n, g,
                                              pxb * 256 + (int)threadIdx.x, 0, true);
    } else if (b < GB + KB) {
        int t = b - GB;
        int pxb = t % 8;
        int n = (t / 8) % N;
        int g = t / (8 * N);
        conv3x3_2px<9, 5, 16, 6, WL, WL, 64>(clf, wtE2, benc2, k_out, n, g,
                                             pxb * 256 + (int)threadIdx.x, 0, true);
    } else {
        int t = b - GB - KB;
        int pxb = t % 32; t /= 32;
        int n = t % N; t /= N;
        int g = t % 3;
        int s = t / 3;
        conv3x3_2px<9, 3, 16, 7, WH, WH, 32>(chf, wtE2, benc2, s ? m_hrhr_pB : m_hrhr_pA,
                                             n, g, pxb * 256 + (int)threadIdx.x, s * 32,
                                             s == 0);
    }
}

// F: chf2 -> m_lrhr partials (co 5x5, ci-split 2)
__global__ __launch_bounds__(256) void conv3x3_F_k(const float* __restrict chf2,
                                                   const float* __restrict wtE,
                                                   const float* __restrict benc,
                                                   float* __restrict pA,
                                                   float* __restrict pB, int N) {
    int t = blockIdx.x;
    int pxb = t % 32; t /= 32;
    int n = t % N; t /= N;
    int g = t % 5;
    int s = t / 5;
    conv3x3_2px<25, 5, 32, 7, WH, WH, 32>(chf2, wtE, benc, s ? pB : pA, n, g,
                                          pxb * 256 + (int)threadIdx.x, s * 32, s == 0);
}

// ------- norm9sum: m_hrhr_n = normalize(mA + mB)  (64-thr blocks, 256*N of them) -------
__global__ void norm9sum_k(const float* __restrict a, const float* __restrict bsrc,
                           float* __restrict dst, int N) {
    int b = blockIdx.x;
    int px = (b % 256) * 64 + threadIdx.x;
    int n = b / 256;
    float m[9];
    const float* ap = a + (size_t)n * 9 * HWH + px;
    const float* bp = bsrc + (size_t)n * 9 * HWH + px;
#pragma unroll
    for (int k = 0; k < 9; k++) m[k] = ap[(size_t)k * HWH] + bp[(size_t)k * HWH];
    normalize_post<3>(m);
    float* dp = dst + (size_t)n * 9 * HWH + px;
#pragma unroll
    for (int k = 0; k < 9; k++) dp[(size_t)k * HWH] = m[k];
}

// ------- norm9: mask_hr_n = normalize(mask_hr) -------
__global__ void norm9_k(const float* __restrict src, float* __restrict dst, int N) {
    int b = blockIdx.x;
    int px = (b % 256) * 64 + threadIdx.x;
    int n = b / 256;
    float m[9];
    normalize_mask<3>(src + (size_t)n * 9 * HWH + px, HWH, m);
    float* dp = dst + (size_t)n * 9 * HWH + px;
#pragma unroll
    for (int k = 0; k < 9; k++) dp[(size_t)k * HWH] = m[k];
}

// ---- shared stage: NCH channel planes of a 128-wide image into tile[NCH][10][136],
//      data at col 4+x (aligned float4 stage, pow2 decode, halo zeroed) ----
template <int NCH>
__device__ __forceinline__ void stage_tile136(const float* __restrict src,
                                              float (*__restrict tile)[10][136], int y0) {
    int tid = threadIdx.x;
    if (tid < 80) {
        int r = tid >> 3, c8 = tid & 7;
        int col = (c8 < 4) ? c8 : 128 + c8;
#pragma unroll
        for (int c = 0; c < NCH; c++) tile[c][r][col] = 0.f;
    }
    int r0 = tid >> 5, q0 = tid & 31;
    int gy0 = y0 + r0 - 1;
    bool v0 = (gy0 >= 0) && (gy0 < WH);
    int e1 = tid + 256;
    int r1 = e1 >> 5, q1 = e1 & 31;
    int gy1 = y0 + r1 - 1;
    bool v1 = (e1 < 320) && (gy1 >= 0) && (gy1 < WH);
#pragma unroll
    for (int c = 0; c < NCH; c++) {
        const float* sp = src + (size_t)c * HWH;
        float4 a = make_float4(0.f, 0.f, 0.f, 0.f);
        if (v0) a = *(const float4*)(sp + gy0 * WH + q0 * 4);
        *(float4*)&tile[c][r0][4 + q0 * 4] = a;
        if (e1 < 320) {
            float4 bb = make_float4(0.f, 0.f, 0.f, 0.f);
            if (v1) bb = *(const float4*)(sp + gy1 * WH + q1 * 4);
            *(float4*)&tile[c][r1][4 + q1 * 4] = bb;
        }
    }
    __syncthreads();
}

// ------- stage D+E: chf2 = 2*chf - carafe(chf, m_hrhr_n, k=3, up=1); LDS-tiled -------
__global__ __launch_bounds__(256) void fuse_de_k(const float* __restrict chf,
                                                 const float* __restrict m9n,
                                                 float* __restrict chf2, int N) {
    __shared__ float tile[8][10][136];  // 43520 B
    int b = blockIdx.x;
    int yt = b & 15;
    int g = (b >> 4) & 7;
    int n = b >> 7;
    int y0 = yt * 8;
    int c0 = g * 8;
    stage_tile136<8>(chf + ((size_t)n * 64 + c0) * HWH, tile, y0);
    const float* mb = m9n + (size_t)n * 9 * HWH;
    float* ob = chf2 + ((size_t)n * 64 + c0) * HWH;
#pragma unroll
    for (int i = 0; i < 4; i++) {
        int lp = threadIdx.x + 256 * i;
        int ly = lp >> 7, lx = lp & 127;
        int px = (y0 + ly) * WH + lx;
        float m[9];
#pragma unroll
        for (int t = 0; t < 9; t++) m[t] = mb[(size_t)t * HWH + px];
        for (int c = 0; c < 8; c++) {
            float center = tile[c][ly + 1][4 + lx];
            float s = 0.f;
#pragma unroll
            for (int t = 0; t < 9; t++)
                s = fmaf(m[t], tile[c][ly + t / 3][3 + lx + t % 3], s);
            ob[(size_t)c * HWH + px] = 2.f * center - s;
        }
    }
}

// ---- stage H+I: mask_lr = (m_lrhr) + carafe(g_out, norm(m_lrhr), k=5, up=2) ----
__global__ void fuse_hi_k(const float* __restrict mA, const float* __restrict mB,
                          const float* __restrict g, float* __restrict mask_lr, int N) {
    int b = blockIdx.x;
    int pxb = b % 64;
    int n = (b / 64) % N;
    int co0 = (b / (64 * N)) * 5;
    int px = pxb * 256 + threadIdx.x;
    int Y = px >> 7, X = px & 127;
    int h = Y >> 1, w = X >> 1;
    const float* mbA = mA + (size_t)n * 25 * HWH + px;
    const float* mbB = mB + (size_t)n * 25 * HWH + px;
    float m[25];
    normalize_mask2<5>(mbA, mbB, HWH, m);
    float acc[5];
#pragma unroll
    for (int j = 0; j < 5; j++) acc[j] = 0.f;
    const float* gb = g + ((size_t)n * 25 + co0) * HWL;
    for (int k = 0; k < 25; k++) {
        int sy = h + k / 5 - 2, sx = w + k % 5 - 2;
        if (sy >= 0 && sy < WL && sx >= 0 && sx < WL) {
            int off = sy * WL + sx;
            float mk = m[k];
#pragma unroll
            for (int j = 0; j < 5; j++)
                acc[j] = fmaf(mk, gb[(size_t)j * HWL + off], acc[j]);
        }
    }
#pragma unroll
    for (int j = 0; j < 5; j++)
        mask_lr[((size_t)(n * 25 + co0 + j)) * HWH + px] =
            mbA[(size_t)(co0 + j) * HWH] + mbB[(size_t)(co0 + j) * HWH] + acc[j];
}

// ---------------- normalize mask_lr -> out0; 64-thr blocks ----------------
__global__ void norm25_k(const float* __restrict mask_lr, float* __restrict out0, int N) {
    int b = blockIdx.x;
    int pxb = b % 256;
    int n = b / 256;
    int px = pxb * 64 + threadIdx.x;
    float m[25];
    normalize_mask<5>(mask_lr + (size_t)n * 25 * HWH + px, HWH, m);
#pragma unroll
    for (int k = 0; k < 25; k++) out0[((size_t)(n * 25 + k)) * HWH + px] = m[k];
}

// ---- stage L: mask_hr = (m_hrhr) + carafe(k_out, out0, k=5, up=2); 3 co-groups of 3 ----
__global__ void fuse_l_k(const float* __restrict m_n, const float* __restrict kf,
                         const float* __restrict mhA, const float* __restrict mhB,
                         float* __restrict mask_hr, int N) {
    int b = blockIdx.x;
    int pxb = b % 64;
    int n = (b / 64) % N;
    int co0 = (b / (64 * N)) * 3;
    int px = pxb * 256 + threadIdx.x;
    int Y = px >> 7, X = px & 127;
    int h = Y >> 1, w = X >> 1;
    float m[25];
#pragma unroll
    for (int k = 0; k < 25; k++) m[k] = m_n[((size_t)(n * 25 + k)) * HWH + px];
    float acc[3];
#pragma unroll
    for (int j = 0; j < 3; j++) acc[j] = 0.f;
    const float* kb = kf + ((size_t)n * 9 + co0) * HWL;
    for (int k = 0; k < 25; k++) {
        int sy = h + k / 5 - 2, sx = w + k % 5 - 2;
        if (sy >= 0 && sy < WL && sx >= 0 && sx < WL) {
            int off = sy * WL + sx;
            float mk = m[k];
#pragma unroll
            for (int j = 0; j < 3; j++)
                acc[j] = fmaf(mk, kb[(size_t)j * HWL + off], acc[j]);
        }
    }
#pragma unroll
    for (int j = 0; j < 3; j++)
        mask_hr[((size_t)(n * 9 + co0 + j)) * HWH + px] =
            mhA[((size_t)(n * 9 + co0 + j)) * HWH + px] +
            mhB[((size_t)(n * 9 + co0 + j)) * HWH + px] + acc[j];
}

// ------------- hr_out = 2*hr - carafe(hr, mask_hr_n, k=3, up=1) -> O1 -------------
#define HRCHG 8
__global__ __launch_bounds__(256) void hr_out_k(const float* __restrict m9n,
                                                const float* __restrict hr,
                                                float* __restrict out1, int N) {
    __shared__ float tile[HRCHG][10][136];  // 43520 B
    int b = blockIdx.x;
    int yt = b & 15;
    int g = (b >> 4) & 31;
    int n = b >> 9;
    int y0 = yt * 8;
    int c0 = g * HRCHG;
    stage_tile136<HRCHG>(hr + ((size_t)n * 256 + c0) * HWH, tile, y0);
    const float* mb = m9n + (size_t)n * 9 * HWH;
    float* ob = out1 + ((size_t)n * 256 + c0) * HWH;
#pragma unroll
    for (int i = 0; i < 4; i++) {
        int lp = threadIdx.x + 256 * i;
        int ly = lp >> 7, lx = lp & 127;
        int px = (y0 + ly) * WH + lx;
        float m[9];
#pragma unroll
        for (int t = 0; t < 9; t++) m[t] = mb[(size_t)t * HWH + px];
        for (int c = 0; c < HRCHG; c++) {
            float center = tile[c][ly + 1][4 + lx];
            float s = 0.f;
#pragma unroll
            for (int t = 0; t < 9; t++)
                s = fmaf(m[t], tile[c][ly + t / 3][3 + lx + t % 3], s);
            ob[(size_t)c * HWH + px] = 2.f * center - s;
        }
    }
}

// ------- lr_out = carafe(lr_feat, out0, k=5, up=2) -> O2 (runs LAST) -------
#define LRCHG 16
__global__ __launch_bounds__(256, 1) void lr_out_k(const float* __restrict m_n,
                                                   const float* __restrict lr,
                                                   float* __restrict out2, int N) {
    __shared__ float tile[LRCHG][12][68];  // 52224 B
    int b = blockIdx.x;
    int yt = b & 7;
    int g = (b >> 3) & 15;
    int n = b >> 7;
    int y0 = yt * 16;
    int hbase = y0 >> 1;
    int c0 = g * LRCHG;
    const float* lrb = lr + ((size_t)n * 256 + c0) * HWL;
    // halo zeros (cols 0,1,66,67 over 12 rows)
    if (threadIdx.x < 48) {
        int r = threadIdx.x >> 2, c4 = threadIdx.x & 3;
        int col = (c4 < 2) ? c4 : 64 + c4;
#pragma unroll
        for (int c = 0; c < LRCHG; c++) tile[c][r][col] = 0.f;
    }
    // data cols 2..65: 32 float2/row x 12 rows, pow2 decode, 8B-aligned LDS writes
#pragma unroll
    for (int c = 0; c < LRCHG; c++) {
        const float* sp = lrb + (size_t)c * HWL;
#pragma unroll
        for (int p = 0; p < 2; p++) {
            int e = threadIdx.x + p * 256;
            if (e < 384) {
                int r = e >> 5, q = e & 31;
                int h = hbase + r - 2;
                float2 v = make_float2(0.f, 0.f);
                if (h >= 0 && h < WL) v = *(const float2*)(sp + h * WL + q * 2);
                *(float2*)&tile[c][r][2 + q * 2] = v;
            }
        }
    }
    __syncthreads();
    const float* mb = m_n + (size_t)n * 25 * HWH;
    float* ob = out2 + ((size_t)n * 256 + c0) * HWH;
#pragma unroll
    for (int i = 0; i < 2; i++) {
        int q = threadIdx.x + 256 * i;
        int qy = q >> 6, qx = q & 63;
        int Y0 = y0 + 2 * qy;
        int X0 = 2 * qx;
        float2 mk0[25], mk1[25];
#pragma unroll
        for (int k = 0; k < 25; k++) {
            mk0[k] = *(const float2*)(mb + (size_t)k * HWH + Y0 * WH + X0);
            mk1[k] = *(const float2*)(mb + (size_t)k * HWH + (Y0 + 1) * WH + X0);
        }
        for (int c = 0; c < LRCHG; c++) {
            float a00 = 0.f, a01 = 0.f, a10 = 0.f, a11 = 0.f;
#pragma unroll
            for (int k = 0; k < 25; k++) {
                float v = tile[c][qy + k / 5][qx + k % 5];
                a00 = fmaf(mk0[k].x, v, a00);
                a01 = fmaf(mk0[k].y, v, a01);
                a10 = fmaf(mk1[k].x, v, a10);
                a11 = fmaf(mk1[k].y, v, a11);
            }
            float* op = ob + (size_t)c * HWH + (size_t)Y0 * WH + X0;
            *(float2*)op = make_float2(a00, a01);
            *(float2*)(op + WH) = make_float2(a10, a11);
        }
    }
}

extern "C" void kernel_launch(void* const* d_in, const int* in_sizes, int n_in, void* d_out,
                              int out_size, void* d_ws, size_t ws_size, hipStream_t stream) {
    const float* hr = (const float*)d_in[0];
    const float* lr = (const float*)d_in[1];
    const float* Whr = (const float*)d_in[2];
    const float* bhr = (const float*)d_in[3];
    const float* Wlr = (const float*)d_in[4];
    const float* blr = (const float*)d_in[5];
    const float* Wenc = (const float*)d_in[6];
    const float* benc = (const float*)d_in[7];
    const float* Wenc2 = (const float*)d_in[8];
    const float* benc2 = (const float*)d_in[9];
    float* out = (float*)d_out;
    const int B = in_sizes[0] / (256 * HWH);  // 2
    (void)d_ws; (void)ws_size;

    float* out0 = out;                           // B*25*HWH  (final: mask_lr_n)
    float* O1 = out + (size_t)B * 25 * HWH;      // B*256*HWH (final: hr_out)
    float* O2 = O1 + (size_t)B * 256 * HWH;      // B*256*HWH (final: lr_out)

    // --- scratch inside O2 (dead before lr_out_k overwrites O2) ---
    float* wbase = O2;                                // 60416 floats of weights
    float* wt_hr = wbase;
    float* wt_lr = wbase + 16384;
    float* wtE = wbase + 32768;
    float* wtE2 = wbase + 51200;
    float* mask_hr = O2 + 60416;                      // B*9*HWH
    float* mask_hr_n = mask_hr + (size_t)B * 9 * HWH; // B*9*HWH (normalized)

    // --- scratch inside O1 (dead before hr_out_k overwrites O1); total 8,339,456 < 8,388,608
    float* chf = O1;                                  // B*64*HWH
    float* chf2 = chf + (size_t)B * 64 * HWH;
    float* clf = chf2 + (size_t)B * 64 * HWH;         // B*64*HWL
    float* m_hrhr_pA = clf + (size_t)B * 64 * HWL;    // B*9*HWH
    float* m_hrhr_pB = m_hrhr_pA + (size_t)B * 9 * HWH;
    float* m_lrhr_pA = m_hrhr_pB + (size_t)B * 9 * HWH;   // B*25*HWH
    float* m_lrhr_pB = m_lrhr_pA + (size_t)B * 25 * HWH;
    float* g_out = m_lrhr_pB + (size_t)B * 25 * HWH;  // B*25*HWL
    float* k_out = g_out + (size_t)B * 25 * HWL;      // B*9*HWL
    float* mask_lr = k_out + (size_t)B * 9 * HWL;     // B*25*HWH
    float* m_hrhr_n = mask_lr + (size_t)B * 25 * HWH; // B*9*HWH (normalized)

    prep_w_k<<<64, 256, 0, stream>>>(Whr, Wlr, Wenc, Wenc2, wbase);
    // A+B: 1x1 convs as LDS-GEMM, scalarized weights
    conv1x1_all_k<<<(HWH / 64) * B + (HWL / 64) * B, 256, 0, stream>>>(
        hr, lr, wt_hr, wt_lr, bhr, blr, chf, clf, B);
    // G + K + C merged, 2px/thread
    conv3x3_CGK_k<<<8 * B * 5 + 8 * B * 2 + 32 * B * 6, 256, 0, stream>>>(
        chf, clf, wtE, wtE2, benc, benc2, m_hrhr_pA, m_hrhr_pB, g_out, k_out, B);
    // normalize m_hrhr once (feeds fuse_de)
    norm9sum_k<<<256 * B, 64, 0, stream>>>(m_hrhr_pA, m_hrhr_pB, m_hrhr_n, B);
    // D+E: chf2 (LDS-tiled, pre-normalized mask)
    fuse_de_k<<<B * 128, 256, 0, stream>>>(chf, m_hrhr_n, chf2, B);
    // F: chf2 -> m_lrhr partials, 2px/thread
    conv3x3_F_k<<<32 * B * 10, 256, 0, stream>>>(chf2, wtE, benc, m_lrhr_pA, m_lrhr_pB, B);
    // H+I: mask_lr
    fuse_hi_k<<<64 * B * 5, 256, 0, stream>>>(m_lrhr_pA, m_lrhr_pB, g_out, mask_lr, B);
    // J: out0 = normalize(mask_lr)
    norm25_k<<<256 * B, 64, 0, stream>>>(mask_lr, out0, B);
    // L: mask_hr
    fuse_l_k<<<64 * B * 3, 256, 0, stream>>>(out0, k_out, m_hrhr_pA, m_hrhr_pB, mask_hr, B);
    // normalize mask_hr once (feeds hr_out)
    norm9_k<<<256 * B, 64, 0, stream>>>(mask_hr, mask_hr_n, B);
    // M+O: hr_out -> O1 (LDS-tiled, pre-normalized mask)
    hr_out_k<<<B * 512, 256, 0, stream>>>(mask_hr_n, hr, O1, B);
    // N: lr_out -> O2 (LDS-tiled)
    lr_out_k<<<B * 128, 256, 0, stream>>>(out0, lr, O2, B);
}